// Round 9
// baseline (110.918 us; speedup 1.0000x reference)
//
#include <hip/hip_runtime.h>
#include <hip/hip_bf16.h>
#include <math.h>

// Dims fixed: S=512, H=4, W=4, D=512, dff=2048, NH=8, depth=64. M = 8192 rows.
//
// Pipeline (6 launches):
//  1. prep: xb,W1b,W2b,Wqb bf16 converts + wsum fold + PE table (512x512 fp32)
//  2. q partials: qp{0,1} = xb @ Wqb^T over K-halves, FP32 out (+pe on z=0)
//     gemm128 MODE 0, split-K=2 -> 512 blocks (2 blocks/CU).
//     FP32 partials: bf16 partials cost ~0.12 absmax on q (round-8 FAIL);
//     fp32 partial + single bf16 rounding in attn_g == round-7 accuracy.
//  3. attn_g (128 blocks): stages qp0f+qp1f (fp32 sum -> bf16 LDS), group
//     attention + fused LN1 -> o1 (f32) + o1b (bf16)
//  4. h1b = relu(o1b @ W1b^T + b1)  (gemm256 MODE 1, 256 blocks)
//  5. FFN2 partials: pz{0,1} = h1b @ W2b^T over K-halves, bf16 out
//     (bf16 partials proven safe here: magnitudes O(1), rounds 2-5)
//  6. out = LN(o1 + pz0 + pz1 + b2)  (ln2_fused)

typedef short short8 __attribute__((ext_vector_type(8)));
typedef float f32x4 __attribute__((ext_vector_type(4)));

#define LN10K_OVER_256 0.03597789207803197f

__device__ __forceinline__ void gload16(const short* g, short* l) {
  __builtin_amdgcn_global_load_lds(
      (const __attribute__((address_space(1))) void*)g,
      (__attribute__((address_space(3))) void*)l, 16, 0, 0);
}

#define BAR() do { asm volatile("" ::: "memory"); \
                   __builtin_amdgcn_s_barrier();  \
                   asm volatile("" ::: "memory"); } while (0)

// paired-row swizzled LDS: conceptual [rows][32 cols] bf16, super-row = 2 rows
// (8 slots of 16B), slot ^= (super_row & 7). Staging writes linear t*8 shorts;
// read-side XOR and pre-swizzled global source are the same involution.
__device__ __forceinline__ short8 ldsfrag(const short* opbuf, int R, int fq) {
  int sr = R >> 1;
  int sp = (((R & 1) << 2) | fq) ^ (sr & 7);
  return *(const short8*)(opbuf + sr * 64 + sp * 8);
}

// ============ 256x256/BK32, 8-wave, 3-deep pipelined bf16 GEMM ============
template<bool DOSTAGE, int WAITK>
__device__ __forceinline__ void tile_step(
    short* ldsb, int cur, int nx, int tt,
    const short* Ag0, const short* Ag1, const short* Bg0, const short* Bg1,
    int w, int fr, int fq, int wm, int wn, f32x4 (&acc)[8][4]) {
  const short* Abuf = ldsb + cur * 16384;
  const short* Bbuf = Abuf + 8192;
  short8 af[4], bfr[4];
#pragma unroll
  for (int m = 0; m < 4; ++m) af[m] = ldsfrag(Abuf, wm + m * 16 + fr, fq);
#pragma unroll
  for (int n = 0; n < 4; ++n) bfr[n] = ldsfrag(Bbuf, wn + n * 16 + fr, fq);
  if (DOSTAGE) {
    int kb = (tt + 2) * 32;
    gload16(Ag0 + kb, ldsb + nx * 16384 + w * 512);
    gload16(Ag1 + kb, ldsb + nx * 16384 + 4096 + w * 512);
  }
  BAR();
  __builtin_amdgcn_s_setprio(1);
#pragma unroll
  for (int m = 0; m < 4; ++m)
#pragma unroll
    for (int n = 0; n < 4; ++n)
      acc[m][n] = __builtin_amdgcn_mfma_f32_16x16x32_bf16(af[m], bfr[n],
                                                          acc[m][n], 0, 0, 0);
  __builtin_amdgcn_s_setprio(0);
  BAR();
#pragma unroll
  for (int m = 0; m < 4; ++m) af[m] = ldsfrag(Abuf, wm + 64 + m * 16 + fr, fq);
  if (DOSTAGE) {
    int kb = (tt + 2) * 32;
    gload16(Bg0 + kb, ldsb + nx * 16384 + 8192 + w * 512);
    gload16(Bg1 + kb, ldsb + nx * 16384 + 8192 + 4096 + w * 512);
  }
  BAR();
  __builtin_amdgcn_s_setprio(1);
#pragma unroll
  for (int m = 0; m < 4; ++m)
#pragma unroll
    for (int n = 0; n < 4; ++n)
      acc[4 + m][n] = __builtin_amdgcn_mfma_f32_16x16x32_bf16(af[m], bfr[n],
                                                              acc[4 + m][n], 0, 0, 0);
  __builtin_amdgcn_s_setprio(0);
  if (WAITK == 4) asm volatile("s_waitcnt vmcnt(4)" ::: "memory");
  else if (WAITK == 0) asm volatile("s_waitcnt vmcnt(0)" ::: "memory");
  BAR();
}

// MODE 1: relu(acc + bias[col]) -> bf16 C0.  (FFN1)
template<int MODE, int NT>
__global__ __launch_bounds__(512) void gemm256(
    const short* __restrict__ A, const short* __restrict__ B,
    const float* __restrict__ bias, short* __restrict__ C0,
    int ldC, int ldA, int ldB) {
  __shared__ short lds[3 * 2 * 8192];  // 96 KiB
  const int t = threadIdx.x;
  const int w = t >> 6, l = t & 63;
  const int fr = l & 15, fq = l >> 4;
  const int wm = (w >> 2) * 128;
  const int wn = (w & 3) * 64;
  const int m0 = blockIdx.y * 256, n0 = blockIdx.x * 256;

  const int scont = (t & 7) ^ ((t >> 3) & 7);
  const int Rbase = ((t >> 3) << 1) | (scont >> 2);
  const int cg = (scont & 3) << 3;
  const short* Ag0 = A + (size_t)(m0 + Rbase) * ldA + cg;
  const short* Ag1 = Ag0 + (size_t)128 * ldA;
  const short* Bg0 = B + (size_t)(n0 + Rbase) * ldB + cg;
  const short* Bg1 = Bg0 + (size_t)128 * ldB;
  short* ldsb = &lds[0];

  gload16(Ag0, ldsb + w * 512);
  gload16(Ag1, ldsb + 4096 + w * 512);
  gload16(Bg0, ldsb + 8192 + w * 512);
  gload16(Bg1, ldsb + 8192 + 4096 + w * 512);
  gload16(Ag0 + 32, ldsb + 16384 + w * 512);
  gload16(Ag1 + 32, ldsb + 16384 + 4096 + w * 512);
  gload16(Bg0 + 32, ldsb + 16384 + 8192 + w * 512);
  gload16(Bg1 + 32, ldsb + 16384 + 8192 + 4096 + w * 512);
  asm volatile("s_waitcnt vmcnt(4)" ::: "memory");
  BAR();

  f32x4 acc[8][4] = {};
  int cur = 0;
#pragma unroll 1
  for (int tt = 0; tt < NT - 2; ++tt) {
    int nx = cur + 2; if (nx >= 3) nx -= 3;
    tile_step<true, 4>(ldsb, cur, nx, tt, Ag0, Ag1, Bg0, Bg1,
                       w, fr, fq, wm, wn, acc);
    if (++cur == 3) cur = 0;
  }
  tile_step<false, 0>(ldsb, cur, 0, NT - 2, Ag0, Ag1, Bg0, Bg1,
                      w, fr, fq, wm, wn, acc);
  { int c2 = cur + 1; if (c2 >= 3) c2 -= 3;
    tile_step<false, -1>(ldsb, c2, 0, NT - 1, Ag0, Ag1, Bg0, Bg1,
                         w, fr, fq, wm, wn, acc); }

  float bv[4];
#pragma unroll
  for (int n = 0; n < 4; ++n) bv[n] = bias[n0 + wn + n * 16 + fr];
#pragma unroll
  for (int mm = 0; mm < 8; ++mm) {
#pragma unroll
    for (int n = 0; n < 4; ++n) {
      int col = n0 + wn + n * 16 + fr;
#pragma unroll
      for (int j = 0; j < 4; ++j) {
        int row = m0 + wm + mm * 16 + fq * 4 + j;
        float v = fmaxf(acc[mm][n][j] + bv[n], 0.f);
        __hip_bfloat16 hb = __float2bfloat16(v);
        C0[(size_t)row * ldC + col] = *(short*)&hb;
      }
    }
  }
}

// ============ 128x128/BK32, 4-wave, 3-deep, split-K=2 bf16 GEMM ============
// MODE 0: FP32 partials -> F0/F1; z=0 adds pe[(row>>4)][col] (bias = PE table).
// MODE 3: bf16 partials -> C0/C1.
template<bool DOSTAGE, int WAITK>
__device__ __forceinline__ void tile_step128(
    short* ldsb, int cur, int nx, int tt, int koff,
    const short* Ag0, const short* Ag1, const short* Bg0, const short* Bg1,
    int w, int fr, int fq, int wm, int wn, f32x4 (&acc)[4][4]) {
  const short* Abuf = ldsb + cur * 8192;
  const short* Bbuf = Abuf + 4096;
  short8 af[4], bfr[4];
#pragma unroll
  for (int m = 0; m < 4; ++m) af[m] = ldsfrag(Abuf, wm + m * 16 + fr, fq);
#pragma unroll
  for (int n = 0; n < 4; ++n) bfr[n] = ldsfrag(Bbuf, wn + n * 16 + fr, fq);
  if (DOSTAGE) {
    int kb = koff + (tt + 2) * 32;
    gload16(Ag0 + kb, ldsb + nx * 8192 + w * 512);
    gload16(Ag1 + kb, ldsb + nx * 8192 + 2048 + w * 512);
    gload16(Bg0 + kb, ldsb + nx * 8192 + 4096 + w * 512);
    gload16(Bg1 + kb, ldsb + nx * 8192 + 6144 + w * 512);
  }
  BAR();
  __builtin_amdgcn_s_setprio(1);
#pragma unroll
  for (int m = 0; m < 4; ++m)
#pragma unroll
    for (int n = 0; n < 4; ++n)
      acc[m][n] = __builtin_amdgcn_mfma_f32_16x16x32_bf16(af[m], bfr[n],
                                                          acc[m][n], 0, 0, 0);
  __builtin_amdgcn_s_setprio(0);
  if (WAITK == 4) asm volatile("s_waitcnt vmcnt(4)" ::: "memory");
  else if (WAITK == 0) asm volatile("s_waitcnt vmcnt(0)" ::: "memory");
  BAR();
}

template<int MODE, int NT>
__global__ __launch_bounds__(256) void gemm128(
    const short* __restrict__ A, const short* __restrict__ B,
    const float* __restrict__ bias,
    short* __restrict__ C0, short* __restrict__ C1,
    float* __restrict__ F0, float* __restrict__ F1,
    int ldC, int ldA, int ldB) {
  __shared__ short lds[3 * 8192];  // 48 KiB -> up to 3 blocks/CU
  const int t = threadIdx.x;
  const int w = t >> 6, l = t & 63;
  const int fr = l & 15, fq = l >> 4;
  const int wm = (w >> 1) * 64;
  const int wn = (w & 1) * 64;
  const int m0 = blockIdx.y * 128, n0 = blockIdx.x * 128;
  const int z = blockIdx.z;
  const int koff = z * (NT * 32);

  const int scont = (t & 7) ^ ((t >> 3) & 7);
  const int Rbase = ((t >> 3) << 1) | (scont >> 2);  // [0,64)
  const int cg = (scont & 3) << 3;
  const short* Ag0 = A + (size_t)(m0 + Rbase) * ldA + cg;
  const short* Ag1 = Ag0 + (size_t)64 * ldA;
  const short* Bg0 = B + (size_t)(n0 + Rbase) * ldB + cg;
  const short* Bg1 = Bg0 + (size_t)64 * ldB;
  short* ldsb = &lds[0];

  gload16(Ag0 + koff, ldsb + w * 512);
  gload16(Ag1 + koff, ldsb + 2048 + w * 512);
  gload16(Bg0 + koff, ldsb + 4096 + w * 512);
  gload16(Bg1 + koff, ldsb + 6144 + w * 512);
  gload16(Ag0 + koff + 32, ldsb + 8192 + w * 512);
  gload16(Ag1 + koff + 32, ldsb + 8192 + 2048 + w * 512);
  gload16(Bg0 + koff + 32, ldsb + 8192 + 4096 + w * 512);
  gload16(Bg1 + koff + 32, ldsb + 8192 + 6144 + w * 512);
  asm volatile("s_waitcnt vmcnt(4)" ::: "memory");
  BAR();

  f32x4 acc[4][4] = {};
  int cur = 0;
#pragma unroll 1
  for (int tt = 0; tt < NT - 2; ++tt) {
    int nx = cur + 2; if (nx >= 3) nx -= 3;
    tile_step128<true, 4>(ldsb, cur, nx, tt, koff, Ag0, Ag1, Bg0, Bg1,
                          w, fr, fq, wm, wn, acc);
    if (++cur == 3) cur = 0;
  }
  tile_step128<false, 0>(ldsb, cur, 0, NT - 2, koff, Ag0, Ag1, Bg0, Bg1,
                         w, fr, fq, wm, wn, acc);
  { int c2 = cur + 1; if (c2 >= 3) c2 -= 3;
    tile_step128<false, -1>(ldsb, c2, 0, NT - 1, koff, Ag0, Ag1, Bg0, Bg1,
                            w, fr, fq, wm, wn, acc); }

#pragma unroll
  for (int mm = 0; mm < 4; ++mm) {
    const float* per = nullptr;
    if (MODE == 0) {
      int s = (m0 + wm + mm * 16) >> 4;  // uniform over fq*4+j within this mm
      per = bias + (size_t)s * 512;      // bias = 512x512 fp32 PE table
    }
#pragma unroll
    for (int n = 0; n < 4; ++n) {
      int col = n0 + wn + n * 16 + fr;
      float pv = (MODE == 0 && z == 0) ? per[col] : 0.f;
#pragma unroll
      for (int j = 0; j < 4; ++j) {
        int row = m0 + wm + mm * 16 + fq * 4 + j;
        float v = acc[mm][n][j] + pv;
        if (MODE == 0) {
          float* myF = z ? F1 : F0;
          myF[(size_t)row * ldC + col] = v;
        } else {
          short* myC = z ? C1 : C0;
          __hip_bfloat16 hb = __float2bfloat16(v);
          myC[(size_t)row * ldC + col] = *(short*)&hb;
        }
      }
    }
  }
}

// ============ prep: converts + wfc fold + PE table, ONE launch ============
__device__ __forceinline__ void cvt8(const float* in, short* out, int i) {
  const float4* p = (const float4*)(in + (size_t)i * 8);
  float4 a = p[0], b = p[1];
  union { __hip_bfloat16 h[8]; short8 s; } u;
  u.h[0] = __float2bfloat16(a.x); u.h[1] = __float2bfloat16(a.y);
  u.h[2] = __float2bfloat16(a.z); u.h[3] = __float2bfloat16(a.w);
  u.h[4] = __float2bfloat16(b.x); u.h[5] = __float2bfloat16(b.y);
  u.h[6] = __float2bfloat16(b.z); u.h[7] = __float2bfloat16(b.w);
  *(short8*)(out + (size_t)i * 8) = u.s;
}

__global__ __launch_bounds__(256) void prep(
    const float* __restrict__ x, const float* __restrict__ W1,
    const float* __restrict__ W2, const float* __restrict__ Wq,
    const float* __restrict__ Wfc,
    short* __restrict__ xb, short* __restrict__ W1b,
    short* __restrict__ W2b, short* __restrict__ Wqb,
    float* __restrict__ wsum, float* __restrict__ pe) {
  int b = blockIdx.x, t = threadIdx.x;
  if (b < 2048) {
    cvt8(x, xb, b * 256 + t);
  } else if (b < 2560) {
    cvt8(W1, W1b, (b - 2048) * 256 + t);
  } else if (b < 3072) {
    cvt8(W2, W2b, (b - 2560) * 256 + t);
  } else if (b < 3200) {
    cvt8(Wq, Wqb, (b - 3072) * 256 + t);
  } else if (b < 3328) {
    int idx = (b - 3200) * 256 + t;  // 32768
    int n = idx >> 6, d = idx & 63;
    float s = 0.f;
#pragma unroll
    for (int j = 0; j < 8; ++j) s += Wfc[(size_t)n * 512 + j * 64 + d];
    wsum[idx] = s;
  } else {
    int idx = (b - 3328) * 256 + t;  // 262144
    int s = idx >> 9, c = idx & 511;
    float f = expf(-(float)(c >> 1) * LN10K_OVER_256);
    float ang = (float)s * f;
    pe[idx] = (c & 1) ? cosf(ang) : sinf(ang);
  }
}

// ============ attn_g: per-group attention + fused LN1 (128 blocks) ============
// Stages q = qp0f + qp1f (fp32 K-split partials) into LDS as bf16 (single rounding).
__global__ __launch_bounds__(256) void attn_g(
    const float* __restrict__ qp0, const float* __restrict__ qp1,
    const float* __restrict__ x,
    const float* __restrict__ wsum, const float* __restrict__ g1,
    const float* __restrict__ be1, float* __restrict__ o1,
    short* __restrict__ o1b) {
  int g = blockIdx.x;
  int hw = g >> 3, i = g & 7;
  int t = threadIdx.x;
  __shared__ short sl[512 * 72];       // [512 rows][64 cols + 8 pad] bf16
  __shared__ float a_[512];
  __shared__ float adist_[512];
  __shared__ float pctx[4][64];
  __shared__ float gb[1024];
  __shared__ float redA[4], redB[4], redMS[2];
  __shared__ float ctxs[64];

  gb[t] = g1[t]; gb[t + 256] = g1[t + 256];
  gb[512 + t] = be1[t]; gb[768 + t] = be1[t + 256];

  {
    size_t boff = ((size_t)hw * 512) * 512 + i * 64;
    const float* q0 = qp0 + boff;
    const float* q1 = qp1 + boff;
    int chunk = t & 7, jr0 = t >> 3;
#pragma unroll
    for (int rep = 0; rep < 16; ++rep) {
      int j = jr0 + rep * 32;
      size_t off = (size_t)j * 512 + chunk * 8;
      float4 a0 = *(const float4*)(q0 + off);
      float4 a1 = *(const float4*)(q0 + off + 4);
      float4 b0 = *(const float4*)(q1 + off);
      float4 b1 = *(const float4*)(q1 + off + 4);
      union { __hip_bfloat16 h[8]; short8 s8; } uo;
      uo.h[0] = __float2bfloat16(a0.x + b0.x);
      uo.h[1] = __float2bfloat16(a0.y + b0.y);
      uo.h[2] = __float2bfloat16(a0.z + b0.z);
      uo.h[3] = __float2bfloat16(a0.w + b0.w);
      uo.h[4] = __float2bfloat16(a1.x + b1.x);
      uo.h[5] = __float2bfloat16(a1.y + b1.y);
      uo.h[6] = __float2bfloat16(a1.z + b1.z);
      uo.h[7] = __float2bfloat16(a1.w + b1.w);
      *(short8*)&sl[j * 72 + chunk * 8] = uo.s8;
    }
  }
  __syncthreads();

  float r0 = 0.f, r1 = 0.f;
#pragma unroll
  for (int c = 0; c < 8; ++c) {
    union { short8 s8; short e[8]; } u0, u1;
    u0.s8 = *(const short8*)&sl[t * 72 + c * 8];
    u1.s8 = *(const short8*)&sl[(t + 256) * 72 + c * 8];
#pragma unroll
    for (int u = 0; u < 8; ++u) {
      r0 += __bfloat162float(*(__hip_bfloat16*)&u0.e[u]);
      r1 += __bfloat162float(*(__hip_bfloat16*)&u1.e[u]);
    }
  }
  float m = fmaxf(r0, r1);
  for (int off = 32; off; off >>= 1) m = fmaxf(m, __shfl_down(m, off));
  int wid = t >> 6, lane = t & 63;
  if (lane == 0) redA[wid] = m;
  __syncthreads();
  if (t == 0) redMS[0] = fmaxf(fmaxf(redA[0], redA[1]), fmaxf(redA[2], redA[3]));
  __syncthreads();
  float M = redMS[0];
  float e0 = expf(r0 - M), e1 = expf(r1 - M);
  float s = e0 + e1;
  for (int off = 32; off; off >>= 1) s += __shfl_down(s, off);
  if (lane == 0) redB[wid] = s;
  __syncthreads();
  if (t == 0) redMS[1] = redB[0] + redB[1] + redB[2] + redB[3];
  __syncthreads();
  float inv = 1.f / redMS[1];
  a_[t] = e0 * inv;
  a_[t + 256] = e1 * inv;
  __syncthreads();

  {
    int d = t & 63, seg = t >> 6;
    float acc = 0.f;
    for (int mm = seg * 128; mm < seg * 128 + 128; ++mm)
      acc += a_[mm] * __bfloat162float(*(__hip_bfloat16*)&sl[mm * 72 + d]);
    pctx[seg][d] = acc;
  }
  __syncthreads();
  if (t < 64) ctxs[t] = pctx[0][t] + pctx[1][t] + pctx[2][t] + pctx[3][t];
  __syncthreads();

  for (int n = t; n < 512; n += 256) {
    const float4* wr = (const float4*)(wsum + (size_t)n * 64);
    float sa = 0.f;
#pragma unroll
    for (int db = 0; db < 16; ++db) {
      float4 wv = wr[db];
      float4 cv = *(const float4*)&ctxs[db * 4];
      sa += cv.x * wv.x + cv.y * wv.y + cv.z * wv.z + cv.w * wv.w;
    }
    adist_[n] = sa;
  }
  __syncthreads();

  const float4* x4 = (const float4*)x;
  int w = t >> 6;
#pragma unroll 1
  for (int u = 0; u < 16; ++u) {
    int j = i * 64 + w * 16 + u;
    size_t R = (size_t)hw * 512 + j;
    float4 xv0 = x4[R * 128 + lane * 2];
    float4 xv1 = x4[R * 128 + lane * 2 + 1];
    float4 a0 = *(const float4*)&adist_[lane * 8];
    float4 a1 = *(const float4*)&adist_[lane * 8 + 4];
    float v[8] = {xv0.x + a0.x, xv0.y + a0.y, xv0.z + a0.z, xv0.w + a0.w,
                  xv1.x + a1.x, xv1.y + a1.y, xv1.z + a1.z, xv1.w + a1.w};
    float sm_ = 0.f, sq = 0.f;
#pragma unroll
    for (int q = 0; q < 8; ++q) { sm_ += v[q]; sq += v[q] * v[q]; }
    for (int off = 32; off; off >>= 1) {
      sm_ += __shfl_xor(sm_, off);
      sq += __shfl_xor(sq, off);
    }
    float mean = sm_ * (1.f / 512.f);
    float var = sq * (1.f / 512.f) - mean * mean;
    float rinv = rsqrtf(var + 1e-5f);
    float o[8];
    union { __hip_bfloat16 h[8]; short8 s8; } ub;
#pragma unroll
    for (int q = 0; q < 8; ++q) {
      int c = lane * 8 + q;
      o[q] = (v[q] - mean) * rinv * gb[c] + gb[512 + c];
      ub.h[q] = __float2bfloat16(o[q]);
    }
    float4 w0 = {o[0], o[1], o[2], o[3]};
    float4 w1 = {o[4], o[5], o[6], o[7]};
    *(float4*)&o1[R * 512 + lane * 8] = w0;
    *(float4*)&o1[R * 512 + lane * 8 + 4] = w1;
    *(short8*)&o1b[R * 512 + lane * 8] = ub.s8;
  }
}

// ============ final LN: out = LN(o1 + pz0 + pz1 + b2) ============
__global__ __launch_bounds__(256) void ln2_fused(
    const float* __restrict__ o1,
    const short* __restrict__ p0, const short* __restrict__ p1,
    const float* __restrict__ b2, const float* __restrict__ gamma,
    const float* __restrict__ beta, float* __restrict__ Out) {
  int r = blockIdx.x;
  int t = threadIdx.x;
  size_t base = (size_t)r * 512;
  float v[2];
#pragma unroll
  for (int h = 0; h < 2; ++h) {
    int c = t + h * 256;
    float f = b2[c];
    f += __bfloat162float(*(const __hip_bfloat16*)&p0[base + c]);
    f += __bfloat162float(*(const __hip_bfloat16*)&p1[base + c]);
    v[h] = o1[base + c] + f;
  }
  float s = v[0] + v[1], sq = v[0] * v[0] + v[1] * v[1];
  __shared__ float red[6];
  __shared__ float redA[4];
  __shared__ float redB[4];
  for (int off = 32; off; off >>= 1) {
    s += __shfl_down(s, off);
    sq += __shfl_down(sq, off);
  }
  int wid = t >> 6, lane = t & 63;
  if (lane == 0) { redA[wid] = s; redB[wid] = sq; }
  __syncthreads();
  if (t == 0) {
    float S = redA[0] + redA[1] + redA[2] + redA[3];
    float Q = redB[0] + redB[1] + redB[2] + redB[3];
    float mean = S * (1.f / 512.f);
    float var = Q * (1.f / 512.f) - mean * mean;
    red[4] = mean;
    red[5] = rsqrtf(var + 1e-5f);
  }
  __syncthreads();
  float mean = red[4], inv = red[5];
  Out[base + t] = (v[0] - mean) * inv * gamma[t] + beta[t];
  Out[base + t + 256] = (v[1] - mean) * inv * gamma[t + 256] + beta[t + 256];
}

extern "C" void kernel_launch(void* const* d_in, const int* in_sizes, int n_in,
                              void* d_out, int out_size, void* d_ws, size_t ws_size,
                              hipStream_t stream) {
  const float* x   = (const float*)d_in[0];
  const float* Wq  = (const float*)d_in[1];
  const float* Wfc = (const float*)d_in[2];
  const float* W1  = (const float*)d_in[3];
  const float* b1  = (const float*)d_in[4];
  const float* W2  = (const float*)d_in[5];
  const float* b2  = (const float*)d_in[6];
  const float* g1  = (const float*)d_in[7];
  const float* be1 = (const float*)d_in[8];
  const float* g2  = (const float*)d_in[9];
  const float* be2 = (const float*)d_in[10];
  float* out = (float*)d_out;

  char* ws = (char*)d_ws;
  float* o1    = (float*)(ws);                  // 16 MB
  short* h1b   = (short*)(ws + (16u << 20));    // 32 MB
  short* pz0   = (short*)(ws + (48u << 20));    // 8 MB
  short* pz1   = (short*)(ws + (56u << 20));    // 8 MB
  short* o1b   = (short*)(ws + (64u << 20));    // 8 MB
  short* W1b   = (short*)(ws + (72u << 20));    // 2 MB
  short* W2b   = (short*)(ws + (74u << 20));    // 2 MB
  short* Wqb   = (short*)(ws + (76u << 20));    // 0.5 MB
  short* xb    = (short*)(ws + (77u << 20));    // 8 MB
  float* qp0f  = (float*)(ws + (85u << 20));    // 16 MB
  float* qp1f  = (float*)(ws + (101u << 20));   // 16 MB
  float* wsum  = (float*)(ws + (117u << 20));   // 128 KB
  float* pe    = (float*)(ws + (117u << 20) + (128u << 10));  // 1 MB (end ~118.2 MB)

  // 1. converts + wfc fold + PE table
  prep<<<4352, 256, 0, stream>>>(x, W1, W2, Wq, Wfc, xb, W1b, W2b, Wqb, wsum, pe);
  // 2. q fp32 partials over K-halves: 512 blocks (2 blocks/CU)
  gemm128<0, 8><<<dim3(4, 64, 2), 256, 0, stream>>>(
      xb, Wqb, pe, nullptr, nullptr, qp0f, qp1f, 512, 512, 512);
  // 3. per-group attention (fp32 partial sum -> bf16 once) + fused LN1
  attn_g<<<128, 256, 0, stream>>>(qp0f, qp1f, x, wsum, g1, be1, o1, o1b);
  // 4. h1b = relu(o1b @ W1b^T + b1); 256 blocks
  gemm256<1, 16><<<dim3(8, 32), 512, 0, stream>>>(
      o1b, W1b, b1, h1b, 2048, 512, 512);
  // 5. FFN2 bf16 partials over K-halves: 512 blocks (2 blocks/CU)
  gemm128<3, 32><<<dim3(4, 64, 2), 256, 0, stream>>>(
      h1b, W2b, nullptr, pz0, pz1, nullptr, nullptr, 512, 2048, 2048);
  // 6. out = LN(o1 + pz0 + pz1 + b2)
  ln2_fused<<<8192, 256, 0, stream>>>(o1, pz0, pz1, b2, g2, be2, out);
}

// Round 10
// 110.535 us; speedup vs baseline: 1.0035x; 1.0035x over previous
//
#include <hip/hip_runtime.h>
#include <hip/hip_bf16.h>
#include <math.h>

// Dims fixed: S=512, H=4, W=4, D=512, dff=2048, NH=8, depth=64. M = 8192 rows.
//
// Pipeline (5 launches):
//  1. prep: xb,W1b,W2b,Wqb bf16 converts + wsum fold + PE table (512x512 fp32)
//  2. attn_g (128 blocks): FUSED q-slice GEMM (512x64x512 MFMA per block,
//     q = xb-slab @ Wqb-slice^T + pe, computed fresh -> bf16 LDS, no global q)
//     + rowsum softmax + ctx + adist + fused LN1 -> o1 (f32) + o1b (bf16)
//  3. h1b = relu(o1b @ W1b^T + b1)  (gemm256 MODE 1, 256 blocks)
//  4. f2b = h1b @ W2b^T + b2        (gemm128, 256 blocks, full K=2048)
//  5. out = LN(o1 + f2b)            (ln2_fused)
//
// Round-9 lesson: split-K gave zero TLP benefit and cost its partial traffic
// (+8 us). These GEMMs are not occupancy-starved at 1 block/CU.

typedef short short8 __attribute__((ext_vector_type(8)));
typedef float f32x4 __attribute__((ext_vector_type(4)));

#define LN10K_OVER_256 0.03597789207803197f

__device__ __forceinline__ void gload16(const short* g, short* l) {
  __builtin_amdgcn_global_load_lds(
      (const __attribute__((address_space(1))) void*)g,
      (__attribute__((address_space(3))) void*)l, 16, 0, 0);
}

#define BAR() do { asm volatile("" ::: "memory"); \
                   __builtin_amdgcn_s_barrier();  \
                   asm volatile("" ::: "memory"); } while (0)

// paired-row swizzled LDS: conceptual [rows][32 cols] bf16, super-row = 2 rows
// (8 slots of 16B), slot ^= (super_row & 7). Staging writes linear t*8 shorts
// per 64-row stripe; read-side XOR and pre-swizzled global source are the same
// involution (verified in gemm128/gemm256 since round 2).
__device__ __forceinline__ short8 ldsfrag(const short* opbuf, int R, int fq) {
  int sr = R >> 1;
  int sp = (((R & 1) << 2) | fq) ^ (sr & 7);
  return *(const short8*)(opbuf + sr * 64 + sp * 8);
}

// ============ 256x256/BK32, 8-wave, 3-deep pipelined bf16 GEMM (FFN1) ============
template<bool DOSTAGE, int WAITK>
__device__ __forceinline__ void tile_step(
    short* ldsb, int cur, int nx, int tt,
    const short* Ag0, const short* Ag1, const short* Bg0, const short* Bg1,
    int w, int fr, int fq, int wm, int wn, f32x4 (&acc)[8][4]) {
  const short* Abuf = ldsb + cur * 16384;
  const short* Bbuf = Abuf + 8192;
  short8 af[4], bfr[4];
#pragma unroll
  for (int m = 0; m < 4; ++m) af[m] = ldsfrag(Abuf, wm + m * 16 + fr, fq);
#pragma unroll
  for (int n = 0; n < 4; ++n) bfr[n] = ldsfrag(Bbuf, wn + n * 16 + fr, fq);
  if (DOSTAGE) {
    int kb = (tt + 2) * 32;
    gload16(Ag0 + kb, ldsb + nx * 16384 + w * 512);
    gload16(Ag1 + kb, ldsb + nx * 16384 + 4096 + w * 512);
  }
  BAR();
  __builtin_amdgcn_s_setprio(1);
#pragma unroll
  for (int m = 0; m < 4; ++m)
#pragma unroll
    for (int n = 0; n < 4; ++n)
      acc[m][n] = __builtin_amdgcn_mfma_f32_16x16x32_bf16(af[m], bfr[n],
                                                          acc[m][n], 0, 0, 0);
  __builtin_amdgcn_s_setprio(0);
  BAR();
#pragma unroll
  for (int m = 0; m < 4; ++m) af[m] = ldsfrag(Abuf, wm + 64 + m * 16 + fr, fq);
  if (DOSTAGE) {
    int kb = (tt + 2) * 32;
    gload16(Bg0 + kb, ldsb + nx * 16384 + 8192 + w * 512);
    gload16(Bg1 + kb, ldsb + nx * 16384 + 8192 + 4096 + w * 512);
  }
  BAR();
  __builtin_amdgcn_s_setprio(1);
#pragma unroll
  for (int m = 0; m < 4; ++m)
#pragma unroll
    for (int n = 0; n < 4; ++n)
      acc[4 + m][n] = __builtin_amdgcn_mfma_f32_16x16x32_bf16(af[m], bfr[n],
                                                              acc[4 + m][n], 0, 0, 0);
  __builtin_amdgcn_s_setprio(0);
  if (WAITK == 4) asm volatile("s_waitcnt vmcnt(4)" ::: "memory");
  else if (WAITK == 0) asm volatile("s_waitcnt vmcnt(0)" ::: "memory");
  BAR();
}

template<int NT>
__global__ __launch_bounds__(512) void gemm256(
    const short* __restrict__ A, const short* __restrict__ B,
    const float* __restrict__ bias, short* __restrict__ C0,
    int ldC, int ldA, int ldB) {
  __shared__ short lds[3 * 2 * 8192];  // 96 KiB
  const int t = threadIdx.x;
  const int w = t >> 6, l = t & 63;
  const int fr = l & 15, fq = l >> 4;
  const int wm = (w >> 2) * 128;
  const int wn = (w & 3) * 64;
  const int m0 = blockIdx.y * 256, n0 = blockIdx.x * 256;

  const int scont = (t & 7) ^ ((t >> 3) & 7);
  const int Rbase = ((t >> 3) << 1) | (scont >> 2);
  const int cg = (scont & 3) << 3;
  const short* Ag0 = A + (size_t)(m0 + Rbase) * ldA + cg;
  const short* Ag1 = Ag0 + (size_t)128 * ldA;
  const short* Bg0 = B + (size_t)(n0 + Rbase) * ldB + cg;
  const short* Bg1 = Bg0 + (size_t)128 * ldB;
  short* ldsb = &lds[0];

  gload16(Ag0, ldsb + w * 512);
  gload16(Ag1, ldsb + 4096 + w * 512);
  gload16(Bg0, ldsb + 8192 + w * 512);
  gload16(Bg1, ldsb + 8192 + 4096 + w * 512);
  gload16(Ag0 + 32, ldsb + 16384 + w * 512);
  gload16(Ag1 + 32, ldsb + 16384 + 4096 + w * 512);
  gload16(Bg0 + 32, ldsb + 16384 + 8192 + w * 512);
  gload16(Bg1 + 32, ldsb + 16384 + 8192 + 4096 + w * 512);
  asm volatile("s_waitcnt vmcnt(4)" ::: "memory");
  BAR();

  f32x4 acc[8][4] = {};
  int cur = 0;
#pragma unroll 1
  for (int tt = 0; tt < NT - 2; ++tt) {
    int nx = cur + 2; if (nx >= 3) nx -= 3;
    tile_step<true, 4>(ldsb, cur, nx, tt, Ag0, Ag1, Bg0, Bg1,
                       w, fr, fq, wm, wn, acc);
    if (++cur == 3) cur = 0;
  }
  tile_step<false, 0>(ldsb, cur, 0, NT - 2, Ag0, Ag1, Bg0, Bg1,
                      w, fr, fq, wm, wn, acc);
  { int c2 = cur + 1; if (c2 >= 3) c2 -= 3;
    tile_step<false, -1>(ldsb, c2, 0, NT - 1, Ag0, Ag1, Bg0, Bg1,
                         w, fr, fq, wm, wn, acc); }

  float bv[4];
#pragma unroll
  for (int n = 0; n < 4; ++n) bv[n] = bias[n0 + wn + n * 16 + fr];
#pragma unroll
  for (int mm = 0; mm < 8; ++mm) {
#pragma unroll
    for (int n = 0; n < 4; ++n) {
      int col = n0 + wn + n * 16 + fr;
#pragma unroll
      for (int j = 0; j < 4; ++j) {
        int row = m0 + wm + mm * 16 + fq * 4 + j;
        float v = fmaxf(acc[mm][n][j] + bv[n], 0.f);
        __hip_bfloat16 hb = __float2bfloat16(v);
        C0[(size_t)row * ldC + col] = *(short*)&hb;
      }
    }
  }
}

// ============ 128x128/BK32, 4-wave, 3-deep bf16 GEMM (FFN2, +bias) ============
template<bool DOSTAGE, int WAITK>
__device__ __forceinline__ void tile_step128(
    short* ldsb, int cur, int nx, int tt,
    const short* Ag0, const short* Ag1, const short* Bg0, const short* Bg1,
    int w, int fr, int fq, int wm, int wn, f32x4 (&acc)[4][4]) {
  const short* Abuf = ldsb + cur * 8192;
  const short* Bbuf = Abuf + 4096;
  short8 af[4], bfr[4];
#pragma unroll
  for (int m = 0; m < 4; ++m) af[m] = ldsfrag(Abuf, wm + m * 16 + fr, fq);
#pragma unroll
  for (int n = 0; n < 4; ++n) bfr[n] = ldsfrag(Bbuf, wn + n * 16 + fr, fq);
  if (DOSTAGE) {
    int kb = (tt + 2) * 32;
    gload16(Ag0 + kb, ldsb + nx * 8192 + w * 512);
    gload16(Ag1 + kb, ldsb + nx * 8192 + 2048 + w * 512);
    gload16(Bg0 + kb, ldsb + nx * 8192 + 4096 + w * 512);
    gload16(Bg1 + kb, ldsb + nx * 8192 + 6144 + w * 512);
  }
  BAR();
  __builtin_amdgcn_s_setprio(1);
#pragma unroll
  for (int m = 0; m < 4; ++m)
#pragma unroll
    for (int n = 0; n < 4; ++n)
      acc[m][n] = __builtin_amdgcn_mfma_f32_16x16x32_bf16(af[m], bfr[n],
                                                          acc[m][n], 0, 0, 0);
  __builtin_amdgcn_s_setprio(0);
  if (WAITK == 4) asm volatile("s_waitcnt vmcnt(4)" ::: "memory");
  else if (WAITK == 0) asm volatile("s_waitcnt vmcnt(0)" ::: "memory");
  BAR();
}

template<int NT>
__global__ __launch_bounds__(256) void gemm128(
    const short* __restrict__ A, const short* __restrict__ B,
    const float* __restrict__ bias, short* __restrict__ C,
    int ldC, int ldA, int ldB) {
  __shared__ short lds[3 * 8192];  // 48 KiB
  const int t = threadIdx.x;
  const int w = t >> 6, l = t & 63;
  const int fr = l & 15, fq = l >> 4;
  const int wm = (w >> 1) * 64;
  const int wn = (w & 1) * 64;
  const int m0 = blockIdx.y * 128, n0 = blockIdx.x * 128;

  const int scont = (t & 7) ^ ((t >> 3) & 7);
  const int Rbase = ((t >> 3) << 1) | (scont >> 2);
  const int cg = (scont & 3) << 3;
  const short* Ag0 = A + (size_t)(m0 + Rbase) * ldA + cg;
  const short* Ag1 = Ag0 + (size_t)64 * ldA;
  const short* Bg0 = B + (size_t)(n0 + Rbase) * ldB + cg;
  const short* Bg1 = Bg0 + (size_t)64 * ldB;
  short* ldsb = &lds[0];

  gload16(Ag0, ldsb + w * 512);
  gload16(Ag1, ldsb + 2048 + w * 512);
  gload16(Bg0, ldsb + 4096 + w * 512);
  gload16(Bg1, ldsb + 6144 + w * 512);
  gload16(Ag0 + 32, ldsb + 8192 + w * 512);
  gload16(Ag1 + 32, ldsb + 8192 + 2048 + w * 512);
  gload16(Bg0 + 32, ldsb + 8192 + 4096 + w * 512);
  gload16(Bg1 + 32, ldsb + 8192 + 6144 + w * 512);
  asm volatile("s_waitcnt vmcnt(4)" ::: "memory");
  BAR();

  f32x4 acc[4][4] = {};
  int cur = 0;
#pragma unroll 1
  for (int tt = 0; tt < NT - 2; ++tt) {
    int nx = cur + 2; if (nx >= 3) nx -= 3;
    tile_step128<true, 4>(ldsb, cur, nx, tt, Ag0, Ag1, Bg0, Bg1,
                          w, fr, fq, wm, wn, acc);
    if (++cur == 3) cur = 0;
  }
  tile_step128<false, 0>(ldsb, cur, 0, NT - 2, Ag0, Ag1, Bg0, Bg1,
                         w, fr, fq, wm, wn, acc);
  { int c2 = cur + 1; if (c2 >= 3) c2 -= 3;
    tile_step128<false, -1>(ldsb, c2, 0, NT - 1, Ag0, Ag1, Bg0, Bg1,
                            w, fr, fq, wm, wn, acc); }

  float bv[4];
#pragma unroll
  for (int n = 0; n < 4; ++n) bv[n] = bias[n0 + wn + n * 16 + fr];
#pragma unroll
  for (int mm = 0; mm < 4; ++mm) {
#pragma unroll
    for (int n = 0; n < 4; ++n) {
      int col = n0 + wn + n * 16 + fr;
#pragma unroll
      for (int j = 0; j < 4; ++j) {
        int row = m0 + wm + mm * 16 + fq * 4 + j;
        float v = acc[mm][n][j] + bv[n];
        __hip_bfloat16 hb = __float2bfloat16(v);
        C[(size_t)row * ldC + col] = *(short*)&hb;
      }
    }
  }
}

// ============ prep: converts + wfc fold + PE table, ONE launch ============
__device__ __forceinline__ void cvt8(const float* in, short* out, int i) {
  const float4* p = (const float4*)(in + (size_t)i * 8);
  float4 a = p[0], b = p[1];
  union { __hip_bfloat16 h[8]; short8 s; } u;
  u.h[0] = __float2bfloat16(a.x); u.h[1] = __float2bfloat16(a.y);
  u.h[2] = __float2bfloat16(a.z); u.h[3] = __float2bfloat16(a.w);
  u.h[4] = __float2bfloat16(b.x); u.h[5] = __float2bfloat16(b.y);
  u.h[6] = __float2bfloat16(b.z); u.h[7] = __float2bfloat16(b.w);
  *(short8*)(out + (size_t)i * 8) = u.s;
}

__global__ __launch_bounds__(256) void prep(
    const float* __restrict__ x, const float* __restrict__ W1,
    const float* __restrict__ W2, const float* __restrict__ Wq,
    const float* __restrict__ Wfc,
    short* __restrict__ xb, short* __restrict__ W1b,
    short* __restrict__ W2b, short* __restrict__ Wqb,
    float* __restrict__ wsum, float* __restrict__ pe) {
  int b = blockIdx.x, t = threadIdx.x;
  if (b < 2048) {
    cvt8(x, xb, b * 256 + t);
  } else if (b < 2560) {
    cvt8(W1, W1b, (b - 2048) * 256 + t);
  } else if (b < 3072) {
    cvt8(W2, W2b, (b - 2560) * 256 + t);
  } else if (b < 3200) {
    cvt8(Wq, Wqb, (b - 3072) * 256 + t);
  } else if (b < 3328) {
    int idx = (b - 3200) * 256 + t;  // 32768
    int n = idx >> 6, d = idx & 63;
    float s = 0.f;
#pragma unroll
    for (int j = 0; j < 8; ++j) s += Wfc[(size_t)n * 512 + j * 64 + d];
    wsum[idx] = s;
  } else {
    int idx = (b - 3328) * 256 + t;  // 262144
    int s = idx >> 9, c = idx & 511;
    float f = expf(-(float)(c >> 1) * LN10K_OVER_256);
    float ang = (float)s * f;
    pe[idx] = (c & 1) ? cosf(ang) : sinf(ang);
  }
}

// ============ attn_g: fused q-slice GEMM + attention + LN1 (128 blocks) ============
// Per block g=(hw,i): q-slice[512 rows][64 cols] = xb-slab @ Wqb-slice^T + pe,
// MFMA'd fresh into LDS (single bf16 rounding == round-7 numerics).
// GEMM: M=512, N=64, K=512; 4 waves (wm=w*128), acc[8][4]; 3-deep pipeline;
// 9 gload16/tile (8 A-issues of 64 rows + 1 B-issue) -> counted vmcnt(9).
template<bool DOSTAGE, int WAITK>
__device__ __forceinline__ void tile_step_attn(
    short* lds0, int cur, int nx, int tt,
    const short* Ag, const short* Bg,
    int w, int fr, int fq, int wm, f32x4 (&acc)[8][4]) {
  const short* Abuf = lds0 + cur * 18432;
  const short* Bbuf = Abuf + 16384;
  short8 af[8], bfr[4];
#pragma unroll
  for (int m = 0; m < 8; ++m) af[m] = ldsfrag(Abuf, wm + m * 16 + fr, fq);
#pragma unroll
  for (int n = 0; n < 4; ++n) bfr[n] = ldsfrag(Bbuf, n * 16 + fr, fq);
  if (DOSTAGE) {
    int kb = (tt + 2) * 32;
    short* dst = lds0 + nx * 18432;
#pragma unroll
    for (int k = 0; k < 8; ++k)
      gload16(Ag + kb + (size_t)(k * 64) * 512, dst + k * 2048 + w * 512);
    gload16(Bg + kb, dst + 16384 + w * 512);
  }
  BAR();
  __builtin_amdgcn_s_setprio(1);
#pragma unroll
  for (int m = 0; m < 8; ++m)
#pragma unroll
    for (int n = 0; n < 4; ++n)
      acc[m][n] = __builtin_amdgcn_mfma_f32_16x16x32_bf16(af[m], bfr[n],
                                                          acc[m][n], 0, 0, 0);
  __builtin_amdgcn_s_setprio(0);
  if (WAITK == 9) asm volatile("s_waitcnt vmcnt(9)" ::: "memory");
  else if (WAITK == 0) asm volatile("s_waitcnt vmcnt(0)" ::: "memory");
  BAR();
}

__global__ __launch_bounds__(256) void attn_g(
    const short* __restrict__ xb, const short* __restrict__ Wqb,
    const float* __restrict__ pe, const float* __restrict__ x,
    const float* __restrict__ wsum, const float* __restrict__ g1,
    const float* __restrict__ be1, float* __restrict__ o1,
    short* __restrict__ o1b) {
  int g = blockIdx.x;
  int hw = g >> 3, i = g & 7;
  int t = threadIdx.x;
  // 3 staging buffers (A 512x32 + B 64x32 bf16 = 18432 shorts each) = 108 KB;
  // sl[512][72] (72 KB) overlays them after the GEMM (lgkmcnt(0)+barrier guard).
  __shared__ short ldsbuf[3 * 18432];
  __shared__ float a_[512];
  __shared__ float adist_[512];
  __shared__ float pctx[4][64];
  __shared__ float gb[1024];
  __shared__ float redA[4], redB[4], redMS[2];
  __shared__ float ctxs[64];
  short* sl = ldsbuf;  // overlay, [512 rows][72 shorts]

  const int w = t >> 6, l = t & 63;
  const int fr = l & 15, fq = l >> 4;
  const int wm = w * 128;
  const int lane = l;

  gb[t] = g1[t]; gb[t + 256] = g1[t + 256];
  gb[512 + t] = be1[t]; gb[768 + t] = be1[t + 256];

  // staging source coords (pre-swizzled involution, per 64-row stripe)
  const int scont = (t & 7) ^ ((t >> 3) & 7);
  const int Rbase = ((t >> 3) << 1) | (scont >> 2);  // [0,64)
  const int cg = (scont & 3) << 3;
  const short* Ag = xb + ((size_t)hw * 512 + Rbase) * 512 + cg;
  const short* Bg = Wqb + ((size_t)i * 64 + Rbase) * 512 + cg;

  // prologue: tiles 0,1
#pragma unroll
  for (int tb = 0; tb < 2; ++tb) {
    short* dst = ldsbuf + tb * 18432;
    int kb = tb * 32;
#pragma unroll
    for (int k = 0; k < 8; ++k)
      gload16(Ag + kb + (size_t)(k * 64) * 512, dst + k * 2048 + w * 512);
    gload16(Bg + kb, dst + 16384 + w * 512);
  }
  asm volatile("s_waitcnt vmcnt(9)" ::: "memory");
  BAR();

  f32x4 acc[8][4] = {};
  int cur = 0;
#pragma unroll 1
  for (int tt = 0; tt < 14; ++tt) {
    int nx = cur + 2; if (nx >= 3) nx -= 3;
    tile_step_attn<true, 9>(ldsbuf, cur, nx, tt, Ag, Bg, w, fr, fq, wm, acc);
    if (++cur == 3) cur = 0;
  }
  tile_step_attn<false, 0>(ldsbuf, cur, 0, 14, Ag, Bg, w, fr, fq, wm, acc);
  { int c2 = cur + 1; if (c2 >= 3) c2 -= 3;
    tile_step_attn<false, -1>(ldsbuf, c2, 0, 15, Ag, Bg, w, fr, fq, wm, acc); }

  // all waves drain their own ds_reads, then barrier -> safe to overlay-write sl
  asm volatile("s_waitcnt lgkmcnt(0)" ::: "memory");
  BAR();

  // epilogue: sl[row][col] = bf16(acc + pe[hw*32 + row>>4][i*64 + col])
#pragma unroll
  for (int m = 0; m < 8; ++m) {
    int rbase = wm + m * 16;
    const float* per = pe + ((size_t)(hw * 32 + (rbase >> 4))) * 512 + i * 64;
#pragma unroll
    for (int n = 0; n < 4; ++n) {
      int col = n * 16 + fr;
      float pv = per[col];
#pragma unroll
      for (int jj = 0; jj < 4; ++jj) {
        int row = rbase + fq * 4 + jj;
        __hip_bfloat16 hb = __float2bfloat16(acc[m][n][jj] + pv);
        sl[row * 72 + col] = *(short*)&hb;
      }
    }
  }
  __syncthreads();

  // rowsums for rows t and t+256
  float r0 = 0.f, r1 = 0.f;
#pragma unroll
  for (int c = 0; c < 8; ++c) {
    union { short8 s8; short e[8]; } u0, u1;
    u0.s8 = *(const short8*)&sl[t * 72 + c * 8];
    u1.s8 = *(const short8*)&sl[(t + 256) * 72 + c * 8];
#pragma unroll
    for (int u = 0; u < 8; ++u) {
      r0 += __bfloat162float(*(__hip_bfloat16*)&u0.e[u]);
      r1 += __bfloat162float(*(__hip_bfloat16*)&u1.e[u]);
    }
  }
  float m = fmaxf(r0, r1);
  for (int off = 32; off; off >>= 1) m = fmaxf(m, __shfl_down(m, off));
  int wid = t >> 6;
  if (lane == 0) redA[wid] = m;
  __syncthreads();
  if (t == 0) redMS[0] = fmaxf(fmaxf(redA[0], redA[1]), fmaxf(redA[2], redA[3]));
  __syncthreads();
  float M = redMS[0];
  float e0 = expf(r0 - M), e1 = expf(r1 - M);
  float s = e0 + e1;
  for (int off = 32; off; off >>= 1) s += __shfl_down(s, off);
  if (lane == 0) redB[wid] = s;
  __syncthreads();
  if (t == 0) redMS[1] = redB[0] + redB[1] + redB[2] + redB[3];
  __syncthreads();
  float inv = 1.f / redMS[1];
  a_[t] = e0 * inv;
  a_[t + 256] = e1 * inv;
  __syncthreads();

  // ctx[d] = sum_j a[j]*slice[j][d]
  {
    int d = t & 63, seg = t >> 6;
    float acc2 = 0.f;
    for (int mm = seg * 128; mm < seg * 128 + 128; ++mm)
      acc2 += a_[mm] * __bfloat162float(*(__hip_bfloat16*)&sl[mm * 72 + d]);
    pctx[seg][d] = acc2;
  }
  __syncthreads();
  if (t < 64) ctxs[t] = pctx[0][t] + pctx[1][t] + pctx[2][t] + pctx[3][t];
  __syncthreads();

  // adist[n] = sum_d ctx[d]*wsum[n][d]
  for (int n = t; n < 512; n += 256) {
    const float4* wr = (const float4*)(wsum + (size_t)n * 64);
    float sa = 0.f;
#pragma unroll
    for (int db = 0; db < 16; ++db) {
      float4 wv = wr[db];
      float4 cv = *(const float4*)&ctxs[db * 4];
      sa += cv.x * wv.x + cv.y * wv.y + cv.z * wv.z + cv.w * wv.w;
    }
    adist_[n] = sa;
  }
  __syncthreads();

  // fused LN1 for this block's 64 rows: R = hw*512 + i*64 + [0,64)
  const float4* x4 = (const float4*)x;
#pragma unroll 1
  for (int u = 0; u < 16; ++u) {
    int j = i * 64 + w * 16 + u;
    size_t R = (size_t)hw * 512 + j;
    float4 xv0 = x4[R * 128 + lane * 2];
    float4 xv1 = x4[R * 128 + lane * 2 + 1];
    float4 a0 = *(const float4*)&adist_[lane * 8];
    float4 a1 = *(const float4*)&adist_[lane * 8 + 4];
    float v[8] = {xv0.x + a0.x, xv0.y + a0.y, xv0.z + a0.z, xv0.w + a0.w,
                  xv1.x + a1.x, xv1.y + a1.y, xv1.z + a1.z, xv1.w + a1.w};
    float sm_ = 0.f, sq = 0.f;
#pragma unroll
    for (int q = 0; q < 8; ++q) { sm_ += v[q]; sq += v[q] * v[q]; }
    for (int off = 32; off; off >>= 1) {
      sm_ += __shfl_xor(sm_, off);
      sq += __shfl_xor(sq, off);
    }
    float mean = sm_ * (1.f / 512.f);
    float var = sq * (1.f / 512.f) - mean * mean;
    float rinv = rsqrtf(var + 1e-5f);
    float o[8];
    union { __hip_bfloat16 h[8]; short8 s8; } ub;
#pragma unroll
    for (int q = 0; q < 8; ++q) {
      int c = lane * 8 + q;
      o[q] = (v[q] - mean) * rinv * gb[c] + gb[512 + c];
      ub.h[q] = __float2bfloat16(o[q]);
    }
    float4 w0 = {o[0], o[1], o[2], o[3]};
    float4 w1 = {o[4], o[5], o[6], o[7]};
    *(float4*)&o1[R * 512 + lane * 8] = w0;
    *(float4*)&o1[R * 512 + lane * 8 + 4] = w1;
    *(short8*)&o1b[R * 512 + lane * 8] = ub.s8;
  }
}

// ============ final LN: out = LN(o1 + f2b), b2 folded into f2b ============
__global__ __launch_bounds__(256) void ln2_fused(
    const float* __restrict__ o1, const short* __restrict__ f2,
    const float* __restrict__ gamma, const float* __restrict__ beta,
    float* __restrict__ Out) {
  int r = blockIdx.x;
  int t = threadIdx.x;
  size_t base = (size_t)r * 512;
  float v0 = o1[base + t] +
             __bfloat162float(*(const __hip_bfloat16*)&f2[base + t]);
  float v1 = o1[base + t + 256] +
             __bfloat162float(*(const __hip_bfloat16*)&f2[base + t + 256]);
  float s = v0 + v1, sq = v0 * v0 + v1 * v1;
  __shared__ float red[6];
  __shared__ float redA[4];
  __shared__ float redB[4];
  for (int off = 32; off; off >>= 1) {
    s += __shfl_down(s, off);
    sq += __shfl_down(sq, off);
  }
  int wid = t >> 6, lane = t & 63;
  if (lane == 0) { redA[wid] = s; redB[wid] = sq; }
  __syncthreads();
  if (t == 0) {
    float S = redA[0] + redA[1] + redA[2] + redA[3];
    float Q = redB[0] + redB[1] + redB[2] + redB[3];
    float mean = S * (1.f / 512.f);
    float var = Q * (1.f / 512.f) - mean * mean;
    red[4] = mean;
    red[5] = rsqrtf(var + 1e-5f);
  }
  __syncthreads();
  float mean = red[4], inv = red[5];
  Out[base + t] = (v0 - mean) * inv * gamma[t] + beta[t];
  Out[base + t + 256] = (v1 - mean) * inv * gamma[t + 256] + beta[t + 256];
}

extern "C" void kernel_launch(void* const* d_in, const int* in_sizes, int n_in,
                              void* d_out, int out_size, void* d_ws, size_t ws_size,
                              hipStream_t stream) {
  const float* x   = (const float*)d_in[0];
  const float* Wq  = (const float*)d_in[1];
  const float* Wfc = (const float*)d_in[2];
  const float* W1  = (const float*)d_in[3];
  const float* b1  = (const float*)d_in[4];
  const float* W2  = (const float*)d_in[5];
  const float* b2  = (const float*)d_in[6];
  const float* g1  = (const float*)d_in[7];
  const float* be1 = (const float*)d_in[8];
  const float* g2  = (const float*)d_in[9];
  const float* be2 = (const float*)d_in[10];
  float* out = (float*)d_out;

  char* ws = (char*)d_ws;
  float* o1   = (float*)(ws);                  // 16 MB
  short* h1b  = (short*)(ws + (16u << 20));    // 32 MB
  short* f2b  = (short*)(ws + (48u << 20));    // 8 MB
  short* o1b  = (short*)(ws + (56u << 20));    // 8 MB
  short* W1b  = (short*)(ws + (64u << 20));    // 2 MB
  short* W2b  = (short*)(ws + (66u << 20));    // 2 MB
  short* Wqb  = (short*)(ws + (68u << 20));    // 0.5 MB
  short* xb   = (short*)(ws + (69u << 20));    // 8 MB
  float* wsum = (float*)(ws + (77u << 20));    // 128 KB
  float* pe   = (float*)(ws + (77u << 20) + (128u << 10));  // 1 MB (end ~78.2 MB)

  // 1. converts + wfc fold + PE table
  prep<<<4352, 256, 0, stream>>>(x, W1, W2, Wq, Wfc, xb, W1b, W2b, Wqb, wsum, pe);
  // 2. fused q-slice GEMM + attention + LN1
  attn_g<<<128, 256, 0, stream>>>(xb, Wqb, pe, x, wsum, g1, be1, o1, o1b);
  // 3. h1b = relu(o1b @ W1b^T + b1)
  gemm256<16><<<dim3(8, 32), 512, 0, stream>>>(
      o1b, W1b, b1, h1b, 2048, 512, 512);
  // 4. f2b = h1b @ W2b^T + b2 (full K, no split)
  gemm128<64><<<dim3(4, 64), 256, 0, stream>>>(
      h1b, W2b, b2, f2b, 512, 2048, 2048);
  // 5. out = LN(o1 + f2b)
  ln2_fused<<<8192, 256, 0, stream>>>(o1, f2b, g2, be2, out);
}

// Round 11
// 100.425 us; speedup vs baseline: 1.1045x; 1.1007x over previous
//
#include <hip/hip_runtime.h>
#include <hip/hip_bf16.h>
#include <math.h>

// Dims fixed: S=512, H=4, W=4, D=512, dff=2048, NH=8, depth=64. M = 8192 rows.
//
// Pipeline (6 launches) — round-7 structure (103us, best) + XCD-chunked
// block swizzle (T1) on the three MFMA GEMMs:
//  1. prep: xb,W1b,W2b,Wqb bf16 converts + wsum fold + PE table (512x512 fp32)
//  2. qb = xb @ Wqb^T + pe          (gemm128 MODE 0, 256 blocks, full K)
//  3. attn_g (128 blocks): group attention + fused LN1 -> o1 (f32) + o1b (bf16)
//  4. h1b = relu(o1b @ W1b^T + b1)  (gemm256 MODE 1, 256 blocks)
//  5. f2b = h1b @ W2b^T + b2        (gemm128 MODE 2, 256 blocks, K=2048)
//  6. out = LN(o1 + f2b)            (ln2_fused)
//
// Ledger: split-K (r9: +8us traffic, no TLP gain) and attn-GEMM fusion
// (r10: 8x xb read amplification, half-GPU grid) both regressed. XCD swizzle:
// consecutive blocks share an A-panel; chunked remap keeps them on one XCD's
// L2 (FFN1 chunk: 4 panels 1MB + W1b 2MB < 4MB L2).

typedef short short8 __attribute__((ext_vector_type(8)));
typedef float f32x4 __attribute__((ext_vector_type(4)));

#define LN10K_OVER_256 0.03597789207803197f

__device__ __forceinline__ void gload16(const short* g, short* l) {
  __builtin_amdgcn_global_load_lds(
      (const __attribute__((address_space(1))) void*)g,
      (__attribute__((address_space(3))) void*)l, 16, 0, 0);
}

#define BAR() do { asm volatile("" ::: "memory"); \
                   __builtin_amdgcn_s_barrier();  \
                   asm volatile("" ::: "memory"); } while (0)

// XCD-chunked bijective swizzle (nwg % 8 == 0): XCD k (= o%8) gets the
// contiguous work chunk [k*nwg/8, (k+1)*nwg/8).
__device__ __forceinline__ void xcd_swizzle(int& bx, int& by) {
  int gx = gridDim.x, nwg = gx * gridDim.y;
  int o = blockIdx.x + blockIdx.y * gx;
  int wid = (o & 7) * (nwg >> 3) + (o >> 3);
  bx = wid % gx;
  by = wid / gx;
}

// paired-row swizzled LDS: conceptual [rows][32 cols] bf16, super-row = 2 rows
// (8 slots of 16B), slot ^= (super_row & 7). Staging writes linear t*8 shorts;
// read-side XOR and pre-swizzled global source are the same involution.
__device__ __forceinline__ short8 ldsfrag(const short* opbuf, int R, int fq) {
  int sr = R >> 1;
  int sp = (((R & 1) << 2) | fq) ^ (sr & 7);
  return *(const short8*)(opbuf + sr * 64 + sp * 8);
}

// ============ 256x256/BK32, 8-wave, 3-deep pipelined bf16 GEMM ============
template<bool DOSTAGE, int WAITK>
__device__ __forceinline__ void tile_step(
    short* ldsb, int cur, int nx, int tt,
    const short* Ag0, const short* Ag1, const short* Bg0, const short* Bg1,
    int w, int fr, int fq, int wm, int wn, f32x4 (&acc)[8][4]) {
  const short* Abuf = ldsb + cur * 16384;
  const short* Bbuf = Abuf + 8192;
  short8 af[4], bfr[4];
#pragma unroll
  for (int m = 0; m < 4; ++m) af[m] = ldsfrag(Abuf, wm + m * 16 + fr, fq);
#pragma unroll
  for (int n = 0; n < 4; ++n) bfr[n] = ldsfrag(Bbuf, wn + n * 16 + fr, fq);
  if (DOSTAGE) {
    int kb = (tt + 2) * 32;
    gload16(Ag0 + kb, ldsb + nx * 16384 + w * 512);
    gload16(Ag1 + kb, ldsb + nx * 16384 + 4096 + w * 512);
  }
  BAR();
  __builtin_amdgcn_s_setprio(1);
#pragma unroll
  for (int m = 0; m < 4; ++m)
#pragma unroll
    for (int n = 0; n < 4; ++n)
      acc[m][n] = __builtin_amdgcn_mfma_f32_16x16x32_bf16(af[m], bfr[n],
                                                          acc[m][n], 0, 0, 0);
  __builtin_amdgcn_s_setprio(0);
  BAR();
#pragma unroll
  for (int m = 0; m < 4; ++m) af[m] = ldsfrag(Abuf, wm + 64 + m * 16 + fr, fq);
  if (DOSTAGE) {
    int kb = (tt + 2) * 32;
    gload16(Bg0 + kb, ldsb + nx * 16384 + 8192 + w * 512);
    gload16(Bg1 + kb, ldsb + nx * 16384 + 8192 + 4096 + w * 512);
  }
  BAR();
  __builtin_amdgcn_s_setprio(1);
#pragma unroll
  for (int m = 0; m < 4; ++m)
#pragma unroll
    for (int n = 0; n < 4; ++n)
      acc[4 + m][n] = __builtin_amdgcn_mfma_f32_16x16x32_bf16(af[m], bfr[n],
                                                              acc[4 + m][n], 0, 0, 0);
  __builtin_amdgcn_s_setprio(0);
  if (WAITK == 4) asm volatile("s_waitcnt vmcnt(4)" ::: "memory");
  else if (WAITK == 0) asm volatile("s_waitcnt vmcnt(0)" ::: "memory");
  BAR();
}

// MODE 1: relu(acc + bias[col]) -> bf16 C0.  (FFN1)
template<int MODE, int NT>
__global__ __launch_bounds__(512) void gemm256(
    const short* __restrict__ A, const short* __restrict__ B,
    const float* __restrict__ bias, short* __restrict__ C0,
    int ldC, int ldA, int ldB) {
  __shared__ short lds[3 * 2 * 8192];  // 96 KiB
  const int t = threadIdx.x;
  const int w = t >> 6, l = t & 63;
  const int fr = l & 15, fq = l >> 4;
  const int wm = (w >> 2) * 128;
  const int wn = (w & 3) * 64;
  int bx, by;
  xcd_swizzle(bx, by);
  const int m0 = by * 256, n0 = bx * 256;

  const int scont = (t & 7) ^ ((t >> 3) & 7);
  const int Rbase = ((t >> 3) << 1) | (scont >> 2);
  const int cg = (scont & 3) << 3;
  const short* Ag0 = A + (size_t)(m0 + Rbase) * ldA + cg;
  const short* Ag1 = Ag0 + (size_t)128 * ldA;
  const short* Bg0 = B + (size_t)(n0 + Rbase) * ldB + cg;
  const short* Bg1 = Bg0 + (size_t)128 * ldB;
  short* ldsb = &lds[0];

  gload16(Ag0, ldsb + w * 512);
  gload16(Ag1, ldsb + 4096 + w * 512);
  gload16(Bg0, ldsb + 8192 + w * 512);
  gload16(Bg1, ldsb + 8192 + 4096 + w * 512);
  gload16(Ag0 + 32, ldsb + 16384 + w * 512);
  gload16(Ag1 + 32, ldsb + 16384 + 4096 + w * 512);
  gload16(Bg0 + 32, ldsb + 16384 + 8192 + w * 512);
  gload16(Bg1 + 32, ldsb + 16384 + 8192 + 4096 + w * 512);
  asm volatile("s_waitcnt vmcnt(4)" ::: "memory");
  BAR();

  f32x4 acc[8][4] = {};
  int cur = 0;
#pragma unroll 1
  for (int tt = 0; tt < NT - 2; ++tt) {
    int nx = cur + 2; if (nx >= 3) nx -= 3;
    tile_step<true, 4>(ldsb, cur, nx, tt, Ag0, Ag1, Bg0, Bg1,
                       w, fr, fq, wm, wn, acc);
    if (++cur == 3) cur = 0;
  }
  tile_step<false, 0>(ldsb, cur, 0, NT - 2, Ag0, Ag1, Bg0, Bg1,
                      w, fr, fq, wm, wn, acc);
  { int c2 = cur + 1; if (c2 >= 3) c2 -= 3;
    tile_step<false, -1>(ldsb, c2, 0, NT - 1, Ag0, Ag1, Bg0, Bg1,
                         w, fr, fq, wm, wn, acc); }

  float bv[4];
#pragma unroll
  for (int n = 0; n < 4; ++n) bv[n] = bias[n0 + wn + n * 16 + fr];
#pragma unroll
  for (int mm = 0; mm < 8; ++mm) {
#pragma unroll
    for (int n = 0; n < 4; ++n) {
      int col = n0 + wn + n * 16 + fr;
#pragma unroll
      for (int j = 0; j < 4; ++j) {
        int row = m0 + wm + mm * 16 + fq * 4 + j;
        float v = fmaxf(acc[mm][n][j] + bv[n], 0.f);
        __hip_bfloat16 hb = __float2bfloat16(v);
        C0[(size_t)row * ldC + col] = *(short*)&hb;
      }
    }
  }
}

// ============ 128x128/BK32, 4-wave, 3-deep pipelined bf16 GEMM ============
// MODE 0: acc + pe[(row>>4)][col] (bias = 512x512 PE table). MODE 2: acc + bias[col].
template<bool DOSTAGE, int WAITK>
__device__ __forceinline__ void tile_step128(
    short* ldsb, int cur, int nx, int tt,
    const short* Ag0, const short* Ag1, const short* Bg0, const short* Bg1,
    int w, int fr, int fq, int wm, int wn, f32x4 (&acc)[4][4]) {
  const short* Abuf = ldsb + cur * 8192;
  const short* Bbuf = Abuf + 4096;
  short8 af[4], bfr[4];
#pragma unroll
  for (int m = 0; m < 4; ++m) af[m] = ldsfrag(Abuf, wm + m * 16 + fr, fq);
#pragma unroll
  for (int n = 0; n < 4; ++n) bfr[n] = ldsfrag(Bbuf, wn + n * 16 + fr, fq);
  if (DOSTAGE) {
    int kb = (tt + 2) * 32;
    gload16(Ag0 + kb, ldsb + nx * 8192 + w * 512);
    gload16(Ag1 + kb, ldsb + nx * 8192 + 2048 + w * 512);
    gload16(Bg0 + kb, ldsb + nx * 8192 + 4096 + w * 512);
    gload16(Bg1 + kb, ldsb + nx * 8192 + 6144 + w * 512);
  }
  BAR();
  __builtin_amdgcn_s_setprio(1);
#pragma unroll
  for (int m = 0; m < 4; ++m)
#pragma unroll
    for (int n = 0; n < 4; ++n)
      acc[m][n] = __builtin_amdgcn_mfma_f32_16x16x32_bf16(af[m], bfr[n],
                                                          acc[m][n], 0, 0, 0);
  __builtin_amdgcn_s_setprio(0);
  if (WAITK == 4) asm volatile("s_waitcnt vmcnt(4)" ::: "memory");
  else if (WAITK == 0) asm volatile("s_waitcnt vmcnt(0)" ::: "memory");
  BAR();
}

template<int MODE, int NT>
__global__ __launch_bounds__(256) void gemm128(
    const short* __restrict__ A, const short* __restrict__ B,
    const float* __restrict__ bias, short* __restrict__ C,
    int ldC, int ldA, int ldB) {
  __shared__ short lds[3 * 8192];  // 48 KiB
  const int t = threadIdx.x;
  const int w = t >> 6, l = t & 63;
  const int fr = l & 15, fq = l >> 4;
  const int wm = (w >> 1) * 64;
  const int wn = (w & 1) * 64;
  int bx, by;
  xcd_swizzle(bx, by);
  const int m0 = by * 128, n0 = bx * 128;

  const int scont = (t & 7) ^ ((t >> 3) & 7);
  const int Rbase = ((t >> 3) << 1) | (scont >> 2);  // [0,64)
  const int cg = (scont & 3) << 3;
  const short* Ag0 = A + (size_t)(m0 + Rbase) * ldA + cg;
  const short* Ag1 = Ag0 + (size_t)64 * ldA;
  const short* Bg0 = B + (size_t)(n0 + Rbase) * ldB + cg;
  const short* Bg1 = Bg0 + (size_t)64 * ldB;
  short* ldsb = &lds[0];

  gload16(Ag0, ldsb + w * 512);
  gload16(Ag1, ldsb + 2048 + w * 512);
  gload16(Bg0, ldsb + 4096 + w * 512);
  gload16(Bg1, ldsb + 6144 + w * 512);
  gload16(Ag0 + 32, ldsb + 8192 + w * 512);
  gload16(Ag1 + 32, ldsb + 8192 + 2048 + w * 512);
  gload16(Bg0 + 32, ldsb + 8192 + 4096 + w * 512);
  gload16(Bg1 + 32, ldsb + 8192 + 6144 + w * 512);
  asm volatile("s_waitcnt vmcnt(4)" ::: "memory");
  BAR();

  f32x4 acc[4][4] = {};
  int cur = 0;
#pragma unroll 1
  for (int tt = 0; tt < NT - 2; ++tt) {
    int nx = cur + 2; if (nx >= 3) nx -= 3;
    tile_step128<true, 4>(ldsb, cur, nx, tt, Ag0, Ag1, Bg0, Bg1,
                          w, fr, fq, wm, wn, acc);
    if (++cur == 3) cur = 0;
  }
  tile_step128<false, 0>(ldsb, cur, 0, NT - 2, Ag0, Ag1, Bg0, Bg1,
                         w, fr, fq, wm, wn, acc);
  { int c2 = cur + 1; if (c2 >= 3) c2 -= 3;
    tile_step128<false, -1>(ldsb, c2, 0, NT - 1, Ag0, Ag1, Bg0, Bg1,
                            w, fr, fq, wm, wn, acc); }

  float bv[4];
  if (MODE == 2) {
#pragma unroll
    for (int n = 0; n < 4; ++n) bv[n] = bias[n0 + wn + n * 16 + fr];
  }
#pragma unroll
  for (int mm = 0; mm < 4; ++mm) {
    const float* per = nullptr;
    if (MODE == 0) {
      int s = (m0 + wm + mm * 16) >> 4;  // uniform over fq*4+j within this mm
      per = bias + (size_t)s * 512;      // bias = 512x512 fp32 PE table
    }
#pragma unroll
    for (int n = 0; n < 4; ++n) {
      int col = n0 + wn + n * 16 + fr;
      float pv = (MODE == 0) ? per[col] : bv[n];
#pragma unroll
      for (int j = 0; j < 4; ++j) {
        int row = m0 + wm + mm * 16 + fq * 4 + j;
        float v = acc[mm][n][j] + pv;
        __hip_bfloat16 hb = __float2bfloat16(v);
        C[(size_t)row * ldC + col] = *(short*)&hb;
      }
    }
  }
}

// ============ prep: converts + wfc fold + PE table, ONE launch ============
__device__ __forceinline__ void cvt8(const float* in, short* out, int i) {
  const float4* p = (const float4*)(in + (size_t)i * 8);
  float4 a = p[0], b = p[1];
  union { __hip_bfloat16 h[8]; short8 s; } u;
  u.h[0] = __float2bfloat16(a.x); u.h[1] = __float2bfloat16(a.y);
  u.h[2] = __float2bfloat16(a.z); u.h[3] = __float2bfloat16(a.w);
  u.h[4] = __float2bfloat16(b.x); u.h[5] = __float2bfloat16(b.y);
  u.h[6] = __float2bfloat16(b.z); u.h[7] = __float2bfloat16(b.w);
  *(short8*)(out + (size_t)i * 8) = u.s;
}

__global__ __launch_bounds__(256) void prep(
    const float* __restrict__ x, const float* __restrict__ W1,
    const float* __restrict__ W2, const float* __restrict__ Wq,
    const float* __restrict__ Wfc,
    short* __restrict__ xb, short* __restrict__ W1b,
    short* __restrict__ W2b, short* __restrict__ Wqb,
    float* __restrict__ wsum, float* __restrict__ pe) {
  int b = blockIdx.x, t = threadIdx.x;
  if (b < 2048) {
    cvt8(x, xb, b * 256 + t);
  } else if (b < 2560) {
    cvt8(W1, W1b, (b - 2048) * 256 + t);
  } else if (b < 3072) {
    cvt8(W2, W2b, (b - 2560) * 256 + t);
  } else if (b < 3200) {
    cvt8(Wq, Wqb, (b - 3072) * 256 + t);
  } else if (b < 3328) {
    int idx = (b - 3200) * 256 + t;  // 32768
    int n = idx >> 6, d = idx & 63;
    float s = 0.f;
#pragma unroll
    for (int j = 0; j < 8; ++j) s += Wfc[(size_t)n * 512 + j * 64 + d];
    wsum[idx] = s;
  } else {
    int idx = (b - 3328) * 256 + t;  // 262144
    int s = idx >> 9, c = idx & 511;
    float f = expf(-(float)(c >> 1) * LN10K_OVER_256);
    float ang = (float)s * f;
    pe[idx] = (c & 1) ? cosf(ang) : sinf(ang);
  }
}

// ============ attn_g: per-group attention + fused LN1 (128 blocks) ============
__global__ __launch_bounds__(256) void attn_g(
    const short* __restrict__ qb, const float* __restrict__ x,
    const float* __restrict__ wsum, const float* __restrict__ g1,
    const float* __restrict__ be1, float* __restrict__ o1,
    short* __restrict__ o1b) {
  int g = blockIdx.x;
  int hw = g >> 3, i = g & 7;
  int t = threadIdx.x;
  __shared__ short sl[512 * 72];       // [512 rows][64 cols + 8 pad] bf16
  __shared__ float a_[512];
  __shared__ float adist_[512];
  __shared__ float pctx[4][64];
  __shared__ float gb[1024];
  __shared__ float redA[4], redB[4], redMS[2];
  __shared__ float ctxs[64];

  gb[t] = g1[t]; gb[t + 256] = g1[t + 256];
  gb[512 + t] = be1[t]; gb[768 + t] = be1[t + 256];

  {
    const short* qsrc = qb + ((size_t)hw * 512) * 512 + i * 64;
    int chunk = t & 7, jr0 = t >> 3;
#pragma unroll
    for (int rep = 0; rep < 16; ++rep) {
      int j = jr0 + rep * 32;
      *(short8*)&sl[j * 72 + chunk * 8] =
          *(const short8*)(qsrc + (size_t)j * 512 + chunk * 8);
    }
  }
  __syncthreads();

  float r0 = 0.f, r1 = 0.f;
#pragma unroll
  for (int c = 0; c < 8; ++c) {
    union { short8 s8; short e[8]; } u0, u1;
    u0.s8 = *(const short8*)&sl[t * 72 + c * 8];
    u1.s8 = *(const short8*)&sl[(t + 256) * 72 + c * 8];
#pragma unroll
    for (int u = 0; u < 8; ++u) {
      r0 += __bfloat162float(*(__hip_bfloat16*)&u0.e[u]);
      r1 += __bfloat162float(*(__hip_bfloat16*)&u1.e[u]);
    }
  }
  float m = fmaxf(r0, r1);
  for (int off = 32; off; off >>= 1) m = fmaxf(m, __shfl_down(m, off));
  int wid = t >> 6, lane = t & 63;
  if (lane == 0) redA[wid] = m;
  __syncthreads();
  if (t == 0) redMS[0] = fmaxf(fmaxf(redA[0], redA[1]), fmaxf(redA[2], redA[3]));
  __syncthreads();
  float M = redMS[0];
  float e0 = expf(r0 - M), e1 = expf(r1 - M);
  float s = e0 + e1;
  for (int off = 32; off; off >>= 1) s += __shfl_down(s, off);
  if (lane == 0) redB[wid] = s;
  __syncthreads();
  if (t == 0) redMS[1] = redB[0] + redB[1] + redB[2] + redB[3];
  __syncthreads();
  float inv = 1.f / redMS[1];
  a_[t] = e0 * inv;
  a_[t + 256] = e1 * inv;
  __syncthreads();

  {
    int d = t & 63, seg = t >> 6;
    float acc = 0.f;
    for (int mm = seg * 128; mm < seg * 128 + 128; ++mm)
      acc += a_[mm] * __bfloat162float(*(__hip_bfloat16*)&sl[mm * 72 + d]);
    pctx[seg][d] = acc;
  }
  __syncthreads();
  if (t < 64) ctxs[t] = pctx[0][t] + pctx[1][t] + pctx[2][t] + pctx[3][t];
  __syncthreads();

  for (int n = t; n < 512; n += 256) {
    const float4* wr = (const float4*)(wsum + (size_t)n * 64);
    float sa = 0.f;
#pragma unroll
    for (int db = 0; db < 16; ++db) {
      float4 wv = wr[db];
      float4 cv = *(const float4*)&ctxs[db * 4];
      sa += cv.x * wv.x + cv.y * wv.y + cv.z * wv.z + cv.w * wv.w;
    }
    adist_[n] = sa;
  }
  __syncthreads();

  const float4* x4 = (const float4*)x;
  int w = t >> 6;
#pragma unroll 1
  for (int u = 0; u < 16; ++u) {
    int j = i * 64 + w * 16 + u;
    size_t R = (size_t)hw * 512 + j;
    float4 xv0 = x4[R * 128 + lane * 2];
    float4 xv1 = x4[R * 128 + lane * 2 + 1];
    float4 a0 = *(const float4*)&adist_[lane * 8];
    float4 a1 = *(const float4*)&adist_[lane * 8 + 4];
    float v[8] = {xv0.x + a0.x, xv0.y + a0.y, xv0.z + a0.z, xv0.w + a0.w,
                  xv1.x + a1.x, xv1.y + a1.y, xv1.z + a1.z, xv1.w + a1.w};
    float sm_ = 0.f, sq = 0.f;
#pragma unroll
    for (int q = 0; q < 8; ++q) { sm_ += v[q]; sq += v[q] * v[q]; }
    for (int off = 32; off; off >>= 1) {
      sm_ += __shfl_xor(sm_, off);
      sq += __shfl_xor(sq, off);
    }
    float mean = sm_ * (1.f / 512.f);
    float var = sq * (1.f / 512.f) - mean * mean;
    float rinv = rsqrtf(var + 1e-5f);
    float o[8];
    union { __hip_bfloat16 h[8]; short8 s8; } ub;
#pragma unroll
    for (int q = 0; q < 8; ++q) {
      int c = lane * 8 + q;
      o[q] = (v[q] - mean) * rinv * gb[c] + gb[512 + c];
      ub.h[q] = __float2bfloat16(o[q]);
    }
    float4 w0 = {o[0], o[1], o[2], o[3]};
    float4 w1 = {o[4], o[5], o[6], o[7]};
    *(float4*)&o1[R * 512 + lane * 8] = w0;
    *(float4*)&o1[R * 512 + lane * 8 + 4] = w1;
    *(short8*)&o1b[R * 512 + lane * 8] = ub.s8;
  }
}

// ============ final LN: out = LN(o1 + f2b), b2 already folded into f2b ============
__global__ __launch_bounds__(256) void ln2_fused(
    const float* __restrict__ o1, const short* __restrict__ f2,
    const float* __restrict__ gamma, const float* __restrict__ beta,
    float* __restrict__ Out) {
  int r = blockIdx.x;
  int t = threadIdx.x;
  size_t base = (size_t)r * 512;
  float v0 = o1[base + t] +
             __bfloat162float(*(const __hip_bfloat16*)&f2[base + t]);
  float v1 = o1[base + t + 256] +
             __bfloat162float(*(const __hip_bfloat16*)&f2[base + t + 256]);
  float s = v0 + v1, sq = v0 * v0 + v1 * v1;
  __shared__ float red[6];
  __shared__ float redA[4];
  __shared__ float redB[4];
  for (int off = 32; off; off >>= 1) {
    s += __shfl_down(s, off);
    sq += __shfl_down(sq, off);
  }
  int wid = t >> 6, lane = t & 63;
  if (lane == 0) { redA[wid] = s; redB[wid] = sq; }
  __syncthreads();
  if (t == 0) {
    float S = redA[0] + redA[1] + redA[2] + redA[3];
    float Q = redB[0] + redB[1] + redB[2] + redB[3];
    float mean = S * (1.f / 512.f);
    float var = Q * (1.f / 512.f) - mean * mean;
    red[4] = mean;
    red[5] = rsqrtf(var + 1e-5f);
  }
  __syncthreads();
  float mean = red[4], inv = red[5];
  Out[base + t] = (v0 - mean) * inv * gamma[t] + beta[t];
  Out[base + t + 256] = (v1 - mean) * inv * gamma[t + 256] + beta[t + 256];
}

extern "C" void kernel_launch(void* const* d_in, const int* in_sizes, int n_in,
                              void* d_out, int out_size, void* d_ws, size_t ws_size,
                              hipStream_t stream) {
  const float* x   = (const float*)d_in[0];
  const float* Wq  = (const float*)d_in[1];
  const float* Wfc = (const float*)d_in[2];
  const float* W1  = (const float*)d_in[3];
  const float* b1  = (const float*)d_in[4];
  const float* W2  = (const float*)d_in[5];
  const float* b2  = (const float*)d_in[6];
  const float* g1  = (const float*)d_in[7];
  const float* be1 = (const float*)d_in[8];
  const float* g2  = (const float*)d_in[9];
  const float* be2 = (const float*)d_in[10];
  float* out = (float*)d_out;

  char* ws = (char*)d_ws;
  float* o1   = (float*)(ws);                  // 16 MB
  short* h1b  = (short*)(ws + (16u << 20));    // 32 MB
  short* f2b  = (short*)(ws + (48u << 20));    // 8 MB
  short* o1b  = (short*)(ws + (56u << 20));    // 8 MB
  short* W1b  = (short*)(ws + (64u << 20));    // 2 MB
  short* W2b  = (short*)(ws + (66u << 20));    // 2 MB
  short* Wqb  = (short*)(ws + (68u << 20));    // 0.5 MB
  short* xb   = (short*)(ws + (69u << 20));    // 8 MB
  short* qb   = (short*)(ws + (77u << 20));    // 8 MB
  float* wsum = (float*)(ws + (85u << 20));    // 128 KB
  float* pe   = (float*)(ws + (85u << 20) + (128u << 10));  // 1 MB (end ~86.2 MB)

  // 1. converts + wfc fold + PE table
  prep<<<4352, 256, 0, stream>>>(x, W1, W2, Wq, Wfc, xb, W1b, W2b, Wqb, wsum, pe);
  // 2. qb = xb @ Wqb^T + pe (bf16); 256 blocks, full K=512
  gemm128<0, 16><<<dim3(4, 64), 256, 0, stream>>>(
      xb, Wqb, pe, qb, 512, 512, 512);
  // 3. per-group attention + fused LN1
  attn_g<<<128, 256, 0, stream>>>(qb, x, wsum, g1, be1, o1, o1b);
  // 4. h1b = relu(o1b @ W1b^T + b1); 256 blocks
  gemm256<1, 16><<<dim3(8, 32), 512, 0, stream>>>(
      o1b, W1b, b1, h1b, 2048, 512, 512);
  // 5. f2b = h1b @ W2b^T + b2; 256 blocks, full K=2048
  gemm128<2, 64><<<dim3(4, 64), 256, 0, stream>>>(
      h1b, W2b, b2, f2b, 512, 2048, 2048);
  // 6. out = LN(o1 + f2b)
  ln2_fused<<<8192, 256, 0, stream>>>(o1, f2b, g2, be2, out);
}

// Round 12
// 94.656 us; speedup vs baseline: 1.1718x; 1.0610x over previous
//
#include <hip/hip_runtime.h>
#include <hip/hip_bf16.h>
#include <math.h>

// Dims fixed: S=512, H=4, W=4, D=512, dff=2048, NH=8, depth=64. M = 8192 rows.
//
// Pipeline (6 launches) — r11 (100.4us) minus the fp32 o1 roundtrip:
//  1. prep: xb,W1b,W2b,Wqb bf16 converts + wsum fold + PE table (512x512 fp32)
//  2. qb = xb @ Wqb^T + pe          (gemm128 MODE 0 + XCD swizzle)
//  3. attn_g (128 blocks): group attention + fused LN1 -> o1b (bf16 ONLY)
//  4. h1b = relu(o1b @ W1b^T + b1)  (gemm256 MODE 1 + XCD swizzle)
//  5. f2b = h1b @ W2b^T + b2        (gemm128 MODE 2 + XCD swizzle, K=2048)
//  6. out = LN(o1b + f2b)           (ln2_fused, wave-per-row short8 loads)
//
// Ledger: split-K (r9) and attn-GEMM fusion (r10) regressed; T1 swizzle +2.6us
// (r11). This round: drop fp32 o1 (-24MB traffic; residual picks up one bf16
// rounding, not amplified downstream) + vectorize ln2 per G13.

typedef short short8 __attribute__((ext_vector_type(8)));
typedef float f32x4 __attribute__((ext_vector_type(4)));

#define LN10K_OVER_256 0.03597789207803197f

__device__ __forceinline__ void gload16(const short* g, short* l) {
  __builtin_amdgcn_global_load_lds(
      (const __attribute__((address_space(1))) void*)g,
      (__attribute__((address_space(3))) void*)l, 16, 0, 0);
}

#define BAR() do { asm volatile("" ::: "memory"); \
                   __builtin_amdgcn_s_barrier();  \
                   asm volatile("" ::: "memory"); } while (0)

// XCD-chunked bijective swizzle (nwg % 8 == 0): XCD k (= o%8) gets the
// contiguous work chunk [k*nwg/8, (k+1)*nwg/8).
__device__ __forceinline__ void xcd_swizzle(int& bx, int& by) {
  int gx = gridDim.x, nwg = gx * gridDim.y;
  int o = blockIdx.x + blockIdx.y * gx;
  int wid = (o & 7) * (nwg >> 3) + (o >> 3);
  bx = wid % gx;
  by = wid / gx;
}

// paired-row swizzled LDS: conceptual [rows][32 cols] bf16, super-row = 2 rows
// (8 slots of 16B), slot ^= (super_row & 7). Staging writes linear t*8 shorts;
// read-side XOR and pre-swizzled global source are the same involution.
__device__ __forceinline__ short8 ldsfrag(const short* opbuf, int R, int fq) {
  int sr = R >> 1;
  int sp = (((R & 1) << 2) | fq) ^ (sr & 7);
  return *(const short8*)(opbuf + sr * 64 + sp * 8);
}

// ============ 256x256/BK32, 8-wave, 3-deep pipelined bf16 GEMM ============
template<bool DOSTAGE, int WAITK>
__device__ __forceinline__ void tile_step(
    short* ldsb, int cur, int nx, int tt,
    const short* Ag0, const short* Ag1, const short* Bg0, const short* Bg1,
    int w, int fr, int fq, int wm, int wn, f32x4 (&acc)[8][4]) {
  const short* Abuf = ldsb + cur * 16384;
  const short* Bbuf = Abuf + 8192;
  short8 af[4], bfr[4];
#pragma unroll
  for (int m = 0; m < 4; ++m) af[m] = ldsfrag(Abuf, wm + m * 16 + fr, fq);
#pragma unroll
  for (int n = 0; n < 4; ++n) bfr[n] = ldsfrag(Bbuf, wn + n * 16 + fr, fq);
  if (DOSTAGE) {
    int kb = (tt + 2) * 32;
    gload16(Ag0 + kb, ldsb + nx * 16384 + w * 512);
    gload16(Ag1 + kb, ldsb + nx * 16384 + 4096 + w * 512);
  }
  BAR();
  __builtin_amdgcn_s_setprio(1);
#pragma unroll
  for (int m = 0; m < 4; ++m)
#pragma unroll
    for (int n = 0; n < 4; ++n)
      acc[m][n] = __builtin_amdgcn_mfma_f32_16x16x32_bf16(af[m], bfr[n],
                                                          acc[m][n], 0, 0, 0);
  __builtin_amdgcn_s_setprio(0);
  BAR();
#pragma unroll
  for (int m = 0; m < 4; ++m) af[m] = ldsfrag(Abuf, wm + 64 + m * 16 + fr, fq);
  if (DOSTAGE) {
    int kb = (tt + 2) * 32;
    gload16(Bg0 + kb, ldsb + nx * 16384 + 8192 + w * 512);
    gload16(Bg1 + kb, ldsb + nx * 16384 + 8192 + 4096 + w * 512);
  }
  BAR();
  __builtin_amdgcn_s_setprio(1);
#pragma unroll
  for (int m = 0; m < 4; ++m)
#pragma unroll
    for (int n = 0; n < 4; ++n)
      acc[4 + m][n] = __builtin_amdgcn_mfma_f32_16x16x32_bf16(af[m], bfr[n],
                                                              acc[4 + m][n], 0, 0, 0);
  __builtin_amdgcn_s_setprio(0);
  if (WAITK == 4) asm volatile("s_waitcnt vmcnt(4)" ::: "memory");
  else if (WAITK == 0) asm volatile("s_waitcnt vmcnt(0)" ::: "memory");
  BAR();
}

// MODE 1: relu(acc + bias[col]) -> bf16 C0.  (FFN1)
template<int MODE, int NT>
__global__ __launch_bounds__(512) void gemm256(
    const short* __restrict__ A, const short* __restrict__ B,
    const float* __restrict__ bias, short* __restrict__ C0,
    int ldC, int ldA, int ldB) {
  __shared__ short lds[3 * 2 * 8192];  // 96 KiB
  const int t = threadIdx.x;
  const int w = t >> 6, l = t & 63;
  const int fr = l & 15, fq = l >> 4;
  const int wm = (w >> 2) * 128;
  const int wn = (w & 3) * 64;
  int bx, by;
  xcd_swizzle(bx, by);
  const int m0 = by * 256, n0 = bx * 256;

  const int scont = (t & 7) ^ ((t >> 3) & 7);
  const int Rbase = ((t >> 3) << 1) | (scont >> 2);
  const int cg = (scont & 3) << 3;
  const short* Ag0 = A + (size_t)(m0 + Rbase) * ldA + cg;
  const short* Ag1 = Ag0 + (size_t)128 * ldA;
  const short* Bg0 = B + (size_t)(n0 + Rbase) * ldB + cg;
  const short* Bg1 = Bg0 + (size_t)128 * ldB;
  short* ldsb = &lds[0];

  gload16(Ag0, ldsb + w * 512);
  gload16(Ag1, ldsb + 4096 + w * 512);
  gload16(Bg0, ldsb + 8192 + w * 512);
  gload16(Bg1, ldsb + 8192 + 4096 + w * 512);
  gload16(Ag0 + 32, ldsb + 16384 + w * 512);
  gload16(Ag1 + 32, ldsb + 16384 + 4096 + w * 512);
  gload16(Bg0 + 32, ldsb + 16384 + 8192 + w * 512);
  gload16(Bg1 + 32, ldsb + 16384 + 8192 + 4096 + w * 512);
  asm volatile("s_waitcnt vmcnt(4)" ::: "memory");
  BAR();

  f32x4 acc[8][4] = {};
  int cur = 0;
#pragma unroll 1
  for (int tt = 0; tt < NT - 2; ++tt) {
    int nx = cur + 2; if (nx >= 3) nx -= 3;
    tile_step<true, 4>(ldsb, cur, nx, tt, Ag0, Ag1, Bg0, Bg1,
                       w, fr, fq, wm, wn, acc);
    if (++cur == 3) cur = 0;
  }
  tile_step<false, 0>(ldsb, cur, 0, NT - 2, Ag0, Ag1, Bg0, Bg1,
                      w, fr, fq, wm, wn, acc);
  { int c2 = cur + 1; if (c2 >= 3) c2 -= 3;
    tile_step<false, -1>(ldsb, c2, 0, NT - 1, Ag0, Ag1, Bg0, Bg1,
                         w, fr, fq, wm, wn, acc); }

  float bv[4];
#pragma unroll
  for (int n = 0; n < 4; ++n) bv[n] = bias[n0 + wn + n * 16 + fr];
#pragma unroll
  for (int mm = 0; mm < 8; ++mm) {
#pragma unroll
    for (int n = 0; n < 4; ++n) {
      int col = n0 + wn + n * 16 + fr;
#pragma unroll
      for (int j = 0; j < 4; ++j) {
        int row = m0 + wm + mm * 16 + fq * 4 + j;
        float v = fmaxf(acc[mm][n][j] + bv[n], 0.f);
        __hip_bfloat16 hb = __float2bfloat16(v);
        C0[(size_t)row * ldC + col] = *(short*)&hb;
      }
    }
  }
}

// ============ 128x128/BK32, 4-wave, 3-deep pipelined bf16 GEMM ============
// MODE 0: acc + pe[(row>>4)][col] (bias = 512x512 PE table). MODE 2: acc + bias[col].
template<bool DOSTAGE, int WAITK>
__device__ __forceinline__ void tile_step128(
    short* ldsb, int cur, int nx, int tt,
    const short* Ag0, const short* Ag1, const short* Bg0, const short* Bg1,
    int w, int fr, int fq, int wm, int wn, f32x4 (&acc)[4][4]) {
  const short* Abuf = ldsb + cur * 8192;
  const short* Bbuf = Abuf + 4096;
  short8 af[4], bfr[4];
#pragma unroll
  for (int m = 0; m < 4; ++m) af[m] = ldsfrag(Abuf, wm + m * 16 + fr, fq);
#pragma unroll
  for (int n = 0; n < 4; ++n) bfr[n] = ldsfrag(Bbuf, wn + n * 16 + fr, fq);
  if (DOSTAGE) {
    int kb = (tt + 2) * 32;
    gload16(Ag0 + kb, ldsb + nx * 8192 + w * 512);
    gload16(Ag1 + kb, ldsb + nx * 8192 + 2048 + w * 512);
    gload16(Bg0 + kb, ldsb + nx * 8192 + 4096 + w * 512);
    gload16(Bg1 + kb, ldsb + nx * 8192 + 6144 + w * 512);
  }
  BAR();
  __builtin_amdgcn_s_setprio(1);
#pragma unroll
  for (int m = 0; m < 4; ++m)
#pragma unroll
    for (int n = 0; n < 4; ++n)
      acc[m][n] = __builtin_amdgcn_mfma_f32_16x16x32_bf16(af[m], bfr[n],
                                                          acc[m][n], 0, 0, 0);
  __builtin_amdgcn_s_setprio(0);
  if (WAITK == 4) asm volatile("s_waitcnt vmcnt(4)" ::: "memory");
  else if (WAITK == 0) asm volatile("s_waitcnt vmcnt(0)" ::: "memory");
  BAR();
}

template<int MODE, int NT>
__global__ __launch_bounds__(256) void gemm128(
    const short* __restrict__ A, const short* __restrict__ B,
    const float* __restrict__ bias, short* __restrict__ C,
    int ldC, int ldA, int ldB) {
  __shared__ short lds[3 * 8192];  // 48 KiB
  const int t = threadIdx.x;
  const int w = t >> 6, l = t & 63;
  const int fr = l & 15, fq = l >> 4;
  const int wm = (w >> 1) * 64;
  const int wn = (w & 1) * 64;
  int bx, by;
  xcd_swizzle(bx, by);
  const int m0 = by * 128, n0 = bx * 128;

  const int scont = (t & 7) ^ ((t >> 3) & 7);
  const int Rbase = ((t >> 3) << 1) | (scont >> 2);  // [0,64)
  const int cg = (scont & 3) << 3;
  const short* Ag0 = A + (size_t)(m0 + Rbase) * ldA + cg;
  const short* Ag1 = Ag0 + (size_t)64 * ldA;
  const short* Bg0 = B + (size_t)(n0 + Rbase) * ldB + cg;
  const short* Bg1 = Bg0 + (size_t)64 * ldB;
  short* ldsb = &lds[0];

  gload16(Ag0, ldsb + w * 512);
  gload16(Ag1, ldsb + 2048 + w * 512);
  gload16(Bg0, ldsb + 4096 + w * 512);
  gload16(Bg1, ldsb + 6144 + w * 512);
  gload16(Ag0 + 32, ldsb + 8192 + w * 512);
  gload16(Ag1 + 32, ldsb + 8192 + 2048 + w * 512);
  gload16(Bg0 + 32, ldsb + 8192 + 4096 + w * 512);
  gload16(Bg1 + 32, ldsb + 8192 + 6144 + w * 512);
  asm volatile("s_waitcnt vmcnt(4)" ::: "memory");
  BAR();

  f32x4 acc[4][4] = {};
  int cur = 0;
#pragma unroll 1
  for (int tt = 0; tt < NT - 2; ++tt) {
    int nx = cur + 2; if (nx >= 3) nx -= 3;
    tile_step128<true, 4>(ldsb, cur, nx, tt, Ag0, Ag1, Bg0, Bg1,
                          w, fr, fq, wm, wn, acc);
    if (++cur == 3) cur = 0;
  }
  tile_step128<false, 0>(ldsb, cur, 0, NT - 2, Ag0, Ag1, Bg0, Bg1,
                         w, fr, fq, wm, wn, acc);
  { int c2 = cur + 1; if (c2 >= 3) c2 -= 3;
    tile_step128<false, -1>(ldsb, c2, 0, NT - 1, Ag0, Ag1, Bg0, Bg1,
                            w, fr, fq, wm, wn, acc); }

  float bv[4];
  if (MODE == 2) {
#pragma unroll
    for (int n = 0; n < 4; ++n) bv[n] = bias[n0 + wn + n * 16 + fr];
  }
#pragma unroll
  for (int mm = 0; mm < 4; ++mm) {
    const float* per = nullptr;
    if (MODE == 0) {
      int s = (m0 + wm + mm * 16) >> 4;  // uniform over fq*4+j within this mm
      per = bias + (size_t)s * 512;      // bias = 512x512 fp32 PE table
    }
#pragma unroll
    for (int n = 0; n < 4; ++n) {
      int col = n0 + wn + n * 16 + fr;
      float pv = (MODE == 0) ? per[col] : bv[n];
#pragma unroll
      for (int j = 0; j < 4; ++j) {
        int row = m0 + wm + mm * 16 + fq * 4 + j;
        float v = acc[mm][n][j] + pv;
        __hip_bfloat16 hb = __float2bfloat16(v);
        C[(size_t)row * ldC + col] = *(short*)&hb;
      }
    }
  }
}

// ============ prep: converts + wfc fold + PE table, ONE launch ============
__device__ __forceinline__ void cvt8(const float* in, short* out, int i) {
  const float4* p = (const float4*)(in + (size_t)i * 8);
  float4 a = p[0], b = p[1];
  union { __hip_bfloat16 h[8]; short8 s; } u;
  u.h[0] = __float2bfloat16(a.x); u.h[1] = __float2bfloat16(a.y);
  u.h[2] = __float2bfloat16(a.z); u.h[3] = __float2bfloat16(a.w);
  u.h[4] = __float2bfloat16(b.x); u.h[5] = __float2bfloat16(b.y);
  u.h[6] = __float2bfloat16(b.z); u.h[7] = __float2bfloat16(b.w);
  *(short8*)(out + (size_t)i * 8) = u.s;
}

__global__ __launch_bounds__(256) void prep(
    const float* __restrict__ x, const float* __restrict__ W1,
    const float* __restrict__ W2, const float* __restrict__ Wq,
    const float* __restrict__ Wfc,
    short* __restrict__ xb, short* __restrict__ W1b,
    short* __restrict__ W2b, short* __restrict__ Wqb,
    float* __restrict__ wsum, float* __restrict__ pe) {
  int b = blockIdx.x, t = threadIdx.x;
  if (b < 2048) {
    cvt8(x, xb, b * 256 + t);
  } else if (b < 2560) {
    cvt8(W1, W1b, (b - 2048) * 256 + t);
  } else if (b < 3072) {
    cvt8(W2, W2b, (b - 2560) * 256 + t);
  } else if (b < 3200) {
    cvt8(Wq, Wqb, (b - 3072) * 256 + t);
  } else if (b < 3328) {
    int idx = (b - 3200) * 256 + t;  // 32768
    int n = idx >> 6, d = idx & 63;
    float s = 0.f;
#pragma unroll
    for (int j = 0; j < 8; ++j) s += Wfc[(size_t)n * 512 + j * 64 + d];
    wsum[idx] = s;
  } else {
    int idx = (b - 3328) * 256 + t;  // 262144
    int s = idx >> 9, c = idx & 511;
    float f = expf(-(float)(c >> 1) * LN10K_OVER_256);
    float ang = (float)s * f;
    pe[idx] = (c & 1) ? cosf(ang) : sinf(ang);
  }
}

// ============ attn_g: per-group attention + fused LN1 (128 blocks) ============
// Output: o1b (bf16) ONLY — fp32 o1 dropped (ln2 residual uses o1b; one extra
// bf16 rounding on the residual, not amplified downstream).
__global__ __launch_bounds__(256) void attn_g(
    const short* __restrict__ qb, const float* __restrict__ x,
    const float* __restrict__ wsum, const float* __restrict__ g1,
    const float* __restrict__ be1, short* __restrict__ o1b) {
  int g = blockIdx.x;
  int hw = g >> 3, i = g & 7;
  int t = threadIdx.x;
  __shared__ short sl[512 * 72];       // [512 rows][64 cols + 8 pad] bf16
  __shared__ float a_[512];
  __shared__ float adist_[512];
  __shared__ float pctx[4][64];
  __shared__ float gb[1024];
  __shared__ float redA[4], redB[4], redMS[2];
  __shared__ float ctxs[64];

  gb[t] = g1[t]; gb[t + 256] = g1[t + 256];
  gb[512 + t] = be1[t]; gb[768 + t] = be1[t + 256];

  {
    const short* qsrc = qb + ((size_t)hw * 512) * 512 + i * 64;
    int chunk = t & 7, jr0 = t >> 3;
#pragma unroll
    for (int rep = 0; rep < 16; ++rep) {
      int j = jr0 + rep * 32;
      *(short8*)&sl[j * 72 + chunk * 8] =
          *(const short8*)(qsrc + (size_t)j * 512 + chunk * 8);
    }
  }
  __syncthreads();

  float r0 = 0.f, r1 = 0.f;
#pragma unroll
  for (int c = 0; c < 8; ++c) {
    union { short8 s8; short e[8]; } u0, u1;
    u0.s8 = *(const short8*)&sl[t * 72 + c * 8];
    u1.s8 = *(const short8*)&sl[(t + 256) * 72 + c * 8];
#pragma unroll
    for (int u = 0; u < 8; ++u) {
      r0 += __bfloat162float(*(__hip_bfloat16*)&u0.e[u]);
      r1 += __bfloat162float(*(__hip_bfloat16*)&u1.e[u]);
    }
  }
  float m = fmaxf(r0, r1);
  for (int off = 32; off; off >>= 1) m = fmaxf(m, __shfl_down(m, off));
  int wid = t >> 6, lane = t & 63;
  if (lane == 0) redA[wid] = m;
  __syncthreads();
  if (t == 0) redMS[0] = fmaxf(fmaxf(redA[0], redA[1]), fmaxf(redA[2], redA[3]));
  __syncthreads();
  float M = redMS[0];
  float e0 = expf(r0 - M), e1 = expf(r1 - M);
  float s = e0 + e1;
  for (int off = 32; off; off >>= 1) s += __shfl_down(s, off);
  if (lane == 0) redB[wid] = s;
  __syncthreads();
  if (t == 0) redMS[1] = redB[0] + redB[1] + redB[2] + redB[3];
  __syncthreads();
  float inv = 1.f / redMS[1];
  a_[t] = e0 * inv;
  a_[t + 256] = e1 * inv;
  __syncthreads();

  {
    int d = t & 63, seg = t >> 6;
    float acc = 0.f;
    for (int mm = seg * 128; mm < seg * 128 + 128; ++mm)
      acc += a_[mm] * __bfloat162float(*(__hip_bfloat16*)&sl[mm * 72 + d]);
    pctx[seg][d] = acc;
  }
  __syncthreads();
  if (t < 64) ctxs[t] = pctx[0][t] + pctx[1][t] + pctx[2][t] + pctx[3][t];
  __syncthreads();

  for (int n = t; n < 512; n += 256) {
    const float4* wr = (const float4*)(wsum + (size_t)n * 64);
    float sa = 0.f;
#pragma unroll
    for (int db = 0; db < 16; ++db) {
      float4 wv = wr[db];
      float4 cv = *(const float4*)&ctxs[db * 4];
      sa += cv.x * wv.x + cv.y * wv.y + cv.z * wv.z + cv.w * wv.w;
    }
    adist_[n] = sa;
  }
  __syncthreads();

  const float4* x4 = (const float4*)x;
  int w = t >> 6;
#pragma unroll 1
  for (int u = 0; u < 16; ++u) {
    int j = i * 64 + w * 16 + u;
    size_t R = (size_t)hw * 512 + j;
    float4 xv0 = x4[R * 128 + lane * 2];
    float4 xv1 = x4[R * 128 + lane * 2 + 1];
    float4 a0 = *(const float4*)&adist_[lane * 8];
    float4 a1 = *(const float4*)&adist_[lane * 8 + 4];
    float v[8] = {xv0.x + a0.x, xv0.y + a0.y, xv0.z + a0.z, xv0.w + a0.w,
                  xv1.x + a1.x, xv1.y + a1.y, xv1.z + a1.z, xv1.w + a1.w};
    float sm_ = 0.f, sq = 0.f;
#pragma unroll
    for (int q = 0; q < 8; ++q) { sm_ += v[q]; sq += v[q] * v[q]; }
    for (int off = 32; off; off >>= 1) {
      sm_ += __shfl_xor(sm_, off);
      sq += __shfl_xor(sq, off);
    }
    float mean = sm_ * (1.f / 512.f);
    float var = sq * (1.f / 512.f) - mean * mean;
    float rinv = rsqrtf(var + 1e-5f);
    union { __hip_bfloat16 h[8]; short8 s8; } ub;
#pragma unroll
    for (int q = 0; q < 8; ++q) {
      int c = lane * 8 + q;
      ub.h[q] = __float2bfloat16((v[q] - mean) * rinv * gb[c] + gb[512 + c]);
    }
    *(short8*)&o1b[R * 512 + lane * 8] = ub.s8;
  }
}

// ============ final LN: out = LN(o1b + f2b); wave-per-row, short8 loads ======
// b2 already folded into f2b. Grid: 2048 blocks x 256 threads (4 rows/block).
__global__ __launch_bounds__(256) void ln2_fused(
    const short* __restrict__ o1b, const short* __restrict__ f2,
    const float* __restrict__ gamma, const float* __restrict__ beta,
    float* __restrict__ Out) {
  int t = threadIdx.x;
  int wv = t >> 6, lane = t & 63;
  size_t r = (size_t)blockIdx.x * 4 + wv;
  size_t base = r * 512 + lane * 8;
  union { short8 s8; short e[8]; } uo, uf;
  uo.s8 = *(const short8*)&o1b[base];
  uf.s8 = *(const short8*)&f2[base];
  float v[8];
  float s = 0.f, sq = 0.f;
#pragma unroll
  for (int k = 0; k < 8; ++k) {
    v[k] = __bfloat162float(*(__hip_bfloat16*)&uo.e[k]) +
           __bfloat162float(*(__hip_bfloat16*)&uf.e[k]);
    s += v[k];
    sq += v[k] * v[k];
  }
  for (int off = 32; off; off >>= 1) {
    s += __shfl_xor(s, off);
    sq += __shfl_xor(sq, off);
  }
  float mean = s * (1.f / 512.f);
  float var = sq * (1.f / 512.f) - mean * mean;
  float inv = rsqrtf(var + 1e-5f);
  int c0 = lane * 8;
  float4 g0 = *(const float4*)&gamma[c0];
  float4 g1v = *(const float4*)&gamma[c0 + 4];
  float4 b0 = *(const float4*)&beta[c0];
  float4 b1v = *(const float4*)&beta[c0 + 4];
  float4 o0, o1v;
  o0.x = (v[0] - mean) * inv * g0.x + b0.x;
  o0.y = (v[1] - mean) * inv * g0.y + b0.y;
  o0.z = (v[2] - mean) * inv * g0.z + b0.z;
  o0.w = (v[3] - mean) * inv * g0.w + b0.w;
  o1v.x = (v[4] - mean) * inv * g1v.x + b1v.x;
  o1v.y = (v[5] - mean) * inv * g1v.y + b1v.y;
  o1v.z = (v[6] - mean) * inv * g1v.z + b1v.z;
  o1v.w = (v[7] - mean) * inv * g1v.w + b1v.w;
  *(float4*)&Out[base] = o0;
  *(float4*)&Out[base + 4] = o1v;
}

extern "C" void kernel_launch(void* const* d_in, const int* in_sizes, int n_in,
                              void* d_out, int out_size, void* d_ws, size_t ws_size,
                              hipStream_t stream) {
  const float* x   = (const float*)d_in[0];
  const float* Wq  = (const float*)d_in[1];
  const float* Wfc = (const float*)d_in[2];
  const float* W1  = (const float*)d_in[3];
  const float* b1  = (const float*)d_in[4];
  const float* W2  = (const float*)d_in[5];
  const float* b2  = (const float*)d_in[6];
  const float* g1  = (const float*)d_in[7];
  const float* be1 = (const float*)d_in[8];
  const float* g2  = (const float*)d_in[9];
  const float* be2 = (const float*)d_in[10];
  float* out = (float*)d_out;

  char* ws = (char*)d_ws;
  short* h1b  = (short*)(ws);                  // 32 MB
  short* f2b  = (short*)(ws + (32u << 20));    // 8 MB
  short* o1b  = (short*)(ws + (40u << 20));    // 8 MB
  short* W1b  = (short*)(ws + (48u << 20));    // 2 MB
  short* W2b  = (short*)(ws + (50u << 20));    // 2 MB
  short* Wqb  = (short*)(ws + (52u << 20));    // 0.5 MB
  short* xb   = (short*)(ws + (53u << 20));    // 8 MB
  short* qb   = (short*)(ws + (61u << 20));    // 8 MB
  float* wsum = (float*)(ws + (69u << 20));    // 128 KB
  float* pe   = (float*)(ws + (69u << 20) + (128u << 10));  // 1 MB (end ~70.2 MB)

  // 1. converts + wfc fold + PE table
  prep<<<4352, 256, 0, stream>>>(x, W1, W2, Wq, Wfc, xb, W1b, W2b, Wqb, wsum, pe);
  // 2. qb = xb @ Wqb^T + pe (bf16); 256 blocks, full K=512
  gemm128<0, 16><<<dim3(4, 64), 256, 0, stream>>>(
      xb, Wqb, pe, qb, 512, 512, 512);
  // 3. per-group attention + fused LN1 -> o1b only
  attn_g<<<128, 256, 0, stream>>>(qb, x, wsum, g1, be1, o1b);
  // 4. h1b = relu(o1b @ W1b^T + b1); 256 blocks
  gemm256<1, 16><<<dim3(8, 32), 512, 0, stream>>>(
      o1b, W1b, b1, h1b, 2048, 512, 512);
  // 5. f2b = h1b @ W2b^T + b2; 256 blocks, full K=2048
  gemm128<2, 64><<<dim3(4, 64), 256, 0, stream>>>(
      h1b, W2b, b2, f2b, 512, 2048, 2048);
  // 6. out = LN(o1b + f2b); 4 rows/block
  ln2_fused<<<2048, 256, 0, stream>>>(o1b, f2b, g2, be2, out);
}

// Round 13
// 93.585 us; speedup vs baseline: 1.1852x; 1.0114x over previous
//
#include <hip/hip_runtime.h>
#include <hip/hip_bf16.h>
#include <math.h>

// Dims fixed: S=512, H=4, W=4, D=512, dff=2048, NH=8, depth=64. M = 8192 rows.
//
// Pipeline (6 launches) — r12 (94.7us) with GEMM sync-overhead cuts
// (bit-identical accumulation order; absmax must stay 0.06884766):
//  1. prep: xb,W1b,W2b,Wqb bf16 converts + wsum fold + PE table
//  2. qb = xb @ Wqb^T + pe          (gemm128 BK=32, unchanged)
//  3. attn_g (128 blocks): group attention + fused LN1 -> o1b (bf16)
//  4. h1b = relu(o1b @ W1b^T + b1)  (gemm256 SINGLE-PHASE: 2 barriers/tile, was 4)
//  5. f2b = h1b @ W2b^T + b2        (gemm128x64: BK=64, 32 tiles, vmcnt(8) — was 64 tiles)
//  6. out = LN(o1b + f2b)           (ln2_fused wave-per-row)
//
// Ledger: split-K (r9) and attn-GEMM fusion (r10) regressed; T1 swizzle +2.6us
// (r11); o1-fp32 drop + ln2 vectorize -5.7us (r12).

typedef short short8 __attribute__((ext_vector_type(8)));
typedef float f32x4 __attribute__((ext_vector_type(4)));

#define LN10K_OVER_256 0.03597789207803197f

__device__ __forceinline__ void gload16(const short* g, short* l) {
  __builtin_amdgcn_global_load_lds(
      (const __attribute__((address_space(1))) void*)g,
      (__attribute__((address_space(3))) void*)l, 16, 0, 0);
}

#define BAR() do { asm volatile("" ::: "memory"); \
                   __builtin_amdgcn_s_barrier();  \
                   asm volatile("" ::: "memory"); } while (0)

// XCD-chunked bijective swizzle (nwg % 8 == 0).
__device__ __forceinline__ void xcd_swizzle(int& bx, int& by) {
  int gx = gridDim.x, nwg = gx * gridDim.y;
  int o = blockIdx.x + blockIdx.y * gx;
  int wid = (o & 7) * (nwg >> 3) + (o >> 3);
  bx = wid % gx;
  by = wid / gx;
}

// paired-row swizzled LDS for 32-col tiles: super-row = 2 rows (128B = 8 slots),
// slot ^= (super_row & 7).
__device__ __forceinline__ short8 ldsfrag(const short* opbuf, int R, int fq) {
  int sr = R >> 1;
  int sp = (((R & 1) << 2) | fq) ^ (sr & 7);
  return *(const short8*)(opbuf + sr * 64 + sp * 8);
}

// row-swizzled LDS for 64-col tiles: one row = 128B = 8 slots, slot ^= (row & 7).
__device__ __forceinline__ short8 ldsfrag64(const short* opbuf, int R, int s) {
  return *(const short8*)(opbuf + R * 64 + ((s ^ (R & 7)) * 8));
}

// ============ 256x256/BK32, 8-wave, 3-deep, SINGLE-PHASE (FFN1) ============
// Per tile: read 12 frags, stage 4 loads, BAR, 32 MFMA, vmcnt(4), BAR.
template<bool DOSTAGE, int WAITK>
__device__ __forceinline__ void tile_step(
    short* ldsb, int cur, int nx, int tt,
    const short* Ag0, const short* Ag1, const short* Bg0, const short* Bg1,
    int w, int fr, int fq, int wm, int wn, f32x4 (&acc)[8][4]) {
  const short* Abuf = ldsb + cur * 16384;
  const short* Bbuf = Abuf + 8192;
  short8 af[8], bfr[4];
#pragma unroll
  for (int m = 0; m < 8; ++m)
    af[m] = ldsfrag(Abuf, wm + (m >> 2) * 64 + (m & 3) * 16 + fr, fq);
#pragma unroll
  for (int n = 0; n < 4; ++n) bfr[n] = ldsfrag(Bbuf, wn + n * 16 + fr, fq);
  if (DOSTAGE) {
    int kb = (tt + 2) * 32;
    gload16(Ag0 + kb, ldsb + nx * 16384 + w * 512);
    gload16(Ag1 + kb, ldsb + nx * 16384 + 4096 + w * 512);
    gload16(Bg0 + kb, ldsb + nx * 16384 + 8192 + w * 512);
    gload16(Bg1 + kb, ldsb + nx * 16384 + 8192 + 4096 + w * 512);
  }
  BAR();
  __builtin_amdgcn_s_setprio(1);
#pragma unroll
  for (int m = 0; m < 4; ++m)
#pragma unroll
    for (int n = 0; n < 4; ++n)
      acc[m][n] = __builtin_amdgcn_mfma_f32_16x16x32_bf16(af[m], bfr[n],
                                                          acc[m][n], 0, 0, 0);
#pragma unroll
  for (int m = 0; m < 4; ++m)
#pragma unroll
    for (int n = 0; n < 4; ++n)
      acc[4 + m][n] = __builtin_amdgcn_mfma_f32_16x16x32_bf16(af[4 + m], bfr[n],
                                                              acc[4 + m][n], 0, 0, 0);
  __builtin_amdgcn_s_setprio(0);
  if (WAITK == 4) asm volatile("s_waitcnt vmcnt(4)" ::: "memory");
  else if (WAITK == 0) asm volatile("s_waitcnt vmcnt(0)" ::: "memory");
  BAR();
}

// MODE 1: relu(acc + bias[col]) -> bf16 C0.
template<int MODE, int NT>
__global__ __launch_bounds__(512) void gemm256(
    const short* __restrict__ A, const short* __restrict__ B,
    const float* __restrict__ bias, short* __restrict__ C0,
    int ldC, int ldA, int ldB) {
  __shared__ short lds[3 * 2 * 8192];  // 96 KiB
  const int t = threadIdx.x;
  const int w = t >> 6, l = t & 63;
  const int fr = l & 15, fq = l >> 4;
  const int wm = (w >> 2) * 128;
  const int wn = (w & 3) * 64;
  int bx, by;
  xcd_swizzle(bx, by);
  const int m0 = by * 256, n0 = bx * 256;

  const int scont = (t & 7) ^ ((t >> 3) & 7);
  const int Rbase = ((t >> 3) << 1) | (scont >> 2);
  const int cg = (scont & 3) << 3;
  const short* Ag0 = A + (size_t)(m0 + Rbase) * ldA + cg;
  const short* Ag1 = Ag0 + (size_t)128 * ldA;
  const short* Bg0 = B + (size_t)(n0 + Rbase) * ldB + cg;
  const short* Bg1 = Bg0 + (size_t)128 * ldB;
  short* ldsb = &lds[0];

  gload16(Ag0, ldsb + w * 512);
  gload16(Ag1, ldsb + 4096 + w * 512);
  gload16(Bg0, ldsb + 8192 + w * 512);
  gload16(Bg1, ldsb + 8192 + 4096 + w * 512);
  gload16(Ag0 + 32, ldsb + 16384 + w * 512);
  gload16(Ag1 + 32, ldsb + 16384 + 4096 + w * 512);
  gload16(Bg0 + 32, ldsb + 16384 + 8192 + w * 512);
  gload16(Bg1 + 32, ldsb + 16384 + 8192 + 4096 + w * 512);
  asm volatile("s_waitcnt vmcnt(4)" ::: "memory");
  BAR();

  f32x4 acc[8][4] = {};
  int cur = 0;
#pragma unroll 1
  for (int tt = 0; tt < NT - 2; ++tt) {
    int nx = cur + 2; if (nx >= 3) nx -= 3;
    tile_step<true, 4>(ldsb, cur, nx, tt, Ag0, Ag1, Bg0, Bg1,
                       w, fr, fq, wm, wn, acc);
    if (++cur == 3) cur = 0;
  }
  tile_step<false, 0>(ldsb, cur, 0, NT - 2, Ag0, Ag1, Bg0, Bg1,
                      w, fr, fq, wm, wn, acc);
  { int c2 = cur + 1; if (c2 >= 3) c2 -= 3;
    tile_step<false, -1>(ldsb, c2, 0, NT - 1, Ag0, Ag1, Bg0, Bg1,
                         w, fr, fq, wm, wn, acc); }

  float bv[4];
#pragma unroll
  for (int n = 0; n < 4; ++n) bv[n] = bias[n0 + wn + n * 16 + fr];
#pragma unroll
  for (int mm = 0; mm < 8; ++mm) {
#pragma unroll
    for (int n = 0; n < 4; ++n) {
      int col = n0 + wn + n * 16 + fr;
#pragma unroll
      for (int j = 0; j < 4; ++j) {
        int row = m0 + wm + mm * 16 + fq * 4 + j;
        float v = fmaxf(acc[mm][n][j] + bv[n], 0.f);
        __hip_bfloat16 hb = __float2bfloat16(v);
        C0[(size_t)row * ldC + col] = *(short*)&hb;
      }
    }
  }
}

// ============ 128x128/BK32, 4-wave, 3-deep (qb GEMM, unchanged) ============
// MODE 0: acc + pe[(row>>4)][col] (bias = 512x512 PE table).
template<bool DOSTAGE, int WAITK>
__device__ __forceinline__ void tile_step128(
    short* ldsb, int cur, int nx, int tt,
    const short* Ag0, const short* Ag1, const short* Bg0, const short* Bg1,
    int w, int fr, int fq, int wm, int wn, f32x4 (&acc)[4][4]) {
  const short* Abuf = ldsb + cur * 8192;
  const short* Bbuf = Abuf + 4096;
  short8 af[4], bfr[4];
#pragma unroll
  for (int m = 0; m < 4; ++m) af[m] = ldsfrag(Abuf, wm + m * 16 + fr, fq);
#pragma unroll
  for (int n = 0; n < 4; ++n) bfr[n] = ldsfrag(Bbuf, wn + n * 16 + fr, fq);
  if (DOSTAGE) {
    int kb = (tt + 2) * 32;
    gload16(Ag0 + kb, ldsb + nx * 8192 + w * 512);
    gload16(Ag1 + kb, ldsb + nx * 8192 + 2048 + w * 512);
    gload16(Bg0 + kb, ldsb + nx * 8192 + 4096 + w * 512);
    gload16(Bg1 + kb, ldsb + nx * 8192 + 6144 + w * 512);
  }
  BAR();
  __builtin_amdgcn_s_setprio(1);
#pragma unroll
  for (int m = 0; m < 4; ++m)
#pragma unroll
    for (int n = 0; n < 4; ++n)
      acc[m][n] = __builtin_amdgcn_mfma_f32_16x16x32_bf16(af[m], bfr[n],
                                                          acc[m][n], 0, 0, 0);
  __builtin_amdgcn_s_setprio(0);
  if (WAITK == 4) asm volatile("s_waitcnt vmcnt(4)" ::: "memory");
  else if (WAITK == 0) asm volatile("s_waitcnt vmcnt(0)" ::: "memory");
  BAR();
}

template<int MODE, int NT>
__global__ __launch_bounds__(256) void gemm128(
    const short* __restrict__ A, const short* __restrict__ B,
    const float* __restrict__ bias, short* __restrict__ C,
    int ldC, int ldA, int ldB) {
  __shared__ short lds[3 * 8192];  // 48 KiB
  const int t = threadIdx.x;
  const int w = t >> 6, l = t & 63;
  const int fr = l & 15, fq = l >> 4;
  const int wm = (w >> 1) * 64;
  const int wn = (w & 1) * 64;
  int bx, by;
  xcd_swizzle(bx, by);
  const int m0 = by * 128, n0 = bx * 128;

  const int scont = (t & 7) ^ ((t >> 3) & 7);
  const int Rbase = ((t >> 3) << 1) | (scont >> 2);
  const int cg = (scont & 3) << 3;
  const short* Ag0 = A + (size_t)(m0 + Rbase) * ldA + cg;
  const short* Ag1 = Ag0 + (size_t)64 * ldA;
  const short* Bg0 = B + (size_t)(n0 + Rbase) * ldB + cg;
  const short* Bg1 = Bg0 + (size_t)64 * ldB;
  short* ldsb = &lds[0];

  gload16(Ag0, ldsb + w * 512);
  gload16(Ag1, ldsb + 2048 + w * 512);
  gload16(Bg0, ldsb + 4096 + w * 512);
  gload16(Bg1, ldsb + 6144 + w * 512);
  gload16(Ag0 + 32, ldsb + 8192 + w * 512);
  gload16(Ag1 + 32, ldsb + 8192 + 2048 + w * 512);
  gload16(Bg0 + 32, ldsb + 8192 + 4096 + w * 512);
  gload16(Bg1 + 32, ldsb + 8192 + 6144 + w * 512);
  asm volatile("s_waitcnt vmcnt(4)" ::: "memory");
  BAR();

  f32x4 acc[4][4] = {};
  int cur = 0;
#pragma unroll 1
  for (int tt = 0; tt < NT - 2; ++tt) {
    int nx = cur + 2; if (nx >= 3) nx -= 3;
    tile_step128<true, 4>(ldsb, cur, nx, tt, Ag0, Ag1, Bg0, Bg1,
                          w, fr, fq, wm, wn, acc);
    if (++cur == 3) cur = 0;
  }
  tile_step128<false, 0>(ldsb, cur, 0, NT - 2, Ag0, Ag1, Bg0, Bg1,
                         w, fr, fq, wm, wn, acc);
  { int c2 = cur + 1; if (c2 >= 3) c2 -= 3;
    tile_step128<false, -1>(ldsb, c2, 0, NT - 1, Ag0, Ag1, Bg0, Bg1,
                            w, fr, fq, wm, wn, acc); }

#pragma unroll
  for (int mm = 0; mm < 4; ++mm) {
    const float* per = nullptr;
    if (MODE == 0) {
      int s = (m0 + wm + mm * 16) >> 4;
      per = bias + (size_t)s * 512;
    }
#pragma unroll
    for (int n = 0; n < 4; ++n) {
      int col = n0 + wn + n * 16 + fr;
      float pv = (MODE == 0) ? per[col] : bias[col];
#pragma unroll
      for (int j = 0; j < 4; ++j) {
        int row = m0 + wm + mm * 16 + fq * 4 + j;
        float v = acc[mm][n][j] + pv;
        __hip_bfloat16 hb = __float2bfloat16(v);
        C[(size_t)row * ldC + col] = *(short*)&hb;
      }
    }
  }
}

// ============ 128x128/BK64, 4-wave, 3-deep (FFN2) ============
// 3 x 32KB buffers; per tile: 8 gloads/wave, 32 MFMA/wave, vmcnt(8), 2 BARs.
// kk-split fragment reads keep register pressure at the BK=32 level.
template<bool DOSTAGE, int WAITK>
__device__ __forceinline__ void tile_step64(
    short* ldsb, int cur, int nx, int tt,
    const short* Ag, const short* Bg, int ldA, int ldB,
    int w, int fr, int fq, int wm, int wn, f32x4 (&acc)[4][4]) {
  const short* Abuf = ldsb + cur * 16384;
  const short* Bbuf = Abuf + 8192;
  short8 af[4], bfr[4];
  // kk = 0 fragments (logical cols 0..31 of this 64-wide K-tile)
#pragma unroll
  for (int m = 0; m < 4; ++m) af[m] = ldsfrag64(Abuf, wm + m * 16 + fr, fq);
#pragma unroll
  for (int n = 0; n < 4; ++n) bfr[n] = ldsfrag64(Bbuf, wn + n * 16 + fr, fq);
  if (DOSTAGE) {
    int kb = (tt + 2) * 64;
    short* dst = ldsb + nx * 16384;
#pragma unroll
    for (int i = 0; i < 4; ++i) {
      gload16(Ag + kb + (size_t)(i * 8) * ldA, dst + (w * 4 + i) * 512);
      gload16(Bg + kb + (size_t)(i * 8) * ldB, dst + 8192 + (w * 4 + i) * 512);
    }
  }
  BAR();
  __builtin_amdgcn_s_setprio(1);
#pragma unroll
  for (int m = 0; m < 4; ++m)
#pragma unroll
    for (int n = 0; n < 4; ++n)
      acc[m][n] = __builtin_amdgcn_mfma_f32_16x16x32_bf16(af[m], bfr[n],
                                                          acc[m][n], 0, 0, 0);
  __builtin_amdgcn_s_setprio(0);
  // kk = 1 fragments (cols 32..63); buf[cur] stays valid until next tile's stage
#pragma unroll
  for (int m = 0; m < 4; ++m) af[m] = ldsfrag64(Abuf, wm + m * 16 + fr, 4 + fq);
#pragma unroll
  for (int n = 0; n < 4; ++n) bfr[n] = ldsfrag64(Bbuf, wn + n * 16 + fr, 4 + fq);
  __builtin_amdgcn_s_setprio(1);
#pragma unroll
  for (int m = 0; m < 4; ++m)
#pragma unroll
    for (int n = 0; n < 4; ++n)
      acc[m][n] = __builtin_amdgcn_mfma_f32_16x16x32_bf16(af[m], bfr[n],
                                                          acc[m][n], 0, 0, 0);
  __builtin_amdgcn_s_setprio(0);
  if (WAITK == 8) asm volatile("s_waitcnt vmcnt(8)" ::: "memory");
  else if (WAITK == 0) asm volatile("s_waitcnt vmcnt(0)" ::: "memory");
  BAR();
}

// MODE 2: acc + bias[col] -> bf16.
template<int NT>
__global__ __launch_bounds__(256) void gemm128x64(
    const short* __restrict__ A, const short* __restrict__ B,
    const float* __restrict__ bias, short* __restrict__ C,
    int ldC, int ldA, int ldB) {
  __shared__ short lds[3 * 16384];  // 96 KiB
  const int t = threadIdx.x;
  const int w = t >> 6, l = t & 63;
  const int fr = l & 15, fq = l >> 4;
  const int wm = (w >> 1) * 64;
  const int wn = (w & 1) * 64;
  int bx, by;
  xcd_swizzle(bx, by);
  const int m0 = by * 128, n0 = bx * 128;

  // staging source (pre-swizzled involution for the 64-col row layout):
  // lane l covers row (l>>3) of its 8-row stripe, col-group (l&7)^(l>>3)
  const int rb = l >> 3;
  const int cgp = ((l & 7) ^ rb) * 8;
  const short* Ag = A + (size_t)(m0 + w * 32 + rb) * ldA + cgp;
  const short* Bg = B + (size_t)(n0 + w * 32 + rb) * ldB + cgp;
  short* ldsb = &lds[0];

  // prologue: tiles 0,1 (8 loads/wave each); wait tile0 (8 left in flight)
#pragma unroll
  for (int tb = 0; tb < 2; ++tb) {
    short* dst = ldsb + tb * 16384;
    int kb = tb * 64;
#pragma unroll
    for (int i = 0; i < 4; ++i) {
      gload16(Ag + kb + (size_t)(i * 8) * ldA, dst + (w * 4 + i) * 512);
      gload16(Bg + kb + (size_t)(i * 8) * ldB, dst + 8192 + (w * 4 + i) * 512);
    }
  }
  asm volatile("s_waitcnt vmcnt(8)" ::: "memory");
  BAR();

  f32x4 acc[4][4] = {};
  int cur = 0;
#pragma unroll 1
  for (int tt = 0; tt < NT - 2; ++tt) {
    int nx = cur + 2; if (nx >= 3) nx -= 3;
    tile_step64<true, 8>(ldsb, cur, nx, tt, Ag, Bg, ldA, ldB,
                         w, fr, fq, wm, wn, acc);
    if (++cur == 3) cur = 0;
  }
  tile_step64<false, 0>(ldsb, cur, 0, NT - 2, Ag, Bg, ldA, ldB,
                        w, fr, fq, wm, wn, acc);
  { int c2 = cur + 1; if (c2 >= 3) c2 -= 3;
    tile_step64<false, -1>(ldsb, c2, 0, NT - 1, Ag, Bg, ldA, ldB,
                           w, fr, fq, wm, wn, acc); }

  float bv[4];
#pragma unroll
  for (int n = 0; n < 4; ++n) bv[n] = bias[n0 + wn + n * 16 + fr];
#pragma unroll
  for (int mm = 0; mm < 4; ++mm) {
#pragma unroll
    for (int n = 0; n < 4; ++n) {
      int col = n0 + wn + n * 16 + fr;
#pragma unroll
      for (int j = 0; j < 4; ++j) {
        int row = m0 + wm + mm * 16 + fq * 4 + j;
        float v = acc[mm][n][j] + bv[n];
        __hip_bfloat16 hb = __float2bfloat16(v);
        C[(size_t)row * ldC + col] = *(short*)&hb;
      }
    }
  }
}

// ============ prep: converts + wfc fold + PE table, ONE launch ============
__device__ __forceinline__ void cvt8(const float* in, short* out, int i) {
  const float4* p = (const float4*)(in + (size_t)i * 8);
  float4 a = p[0], b = p[1];
  union { __hip_bfloat16 h[8]; short8 s; } u;
  u.h[0] = __float2bfloat16(a.x); u.h[1] = __float2bfloat16(a.y);
  u.h[2] = __float2bfloat16(a.z); u.h[3] = __float2bfloat16(a.w);
  u.h[4] = __float2bfloat16(b.x); u.h[5] = __float2bfloat16(b.y);
  u.h[6] = __float2bfloat16(b.z); u.h[7] = __float2bfloat16(b.w);
  *(short8*)(out + (size_t)i * 8) = u.s;
}

__global__ __launch_bounds__(256) void prep(
    const float* __restrict__ x, const float* __restrict__ W1,
    const float* __restrict__ W2, const float* __restrict__ Wq,
    const float* __restrict__ Wfc,
    short* __restrict__ xb, short* __restrict__ W1b,
    short* __restrict__ W2b, short* __restrict__ Wqb,
    float* __restrict__ wsum, float* __restrict__ pe) {
  int b = blockIdx.x, t = threadIdx.x;
  if (b < 2048) {
    cvt8(x, xb, b * 256 + t);
  } else if (b < 2560) {
    cvt8(W1, W1b, (b - 2048) * 256 + t);
  } else if (b < 3072) {
    cvt8(W2, W2b, (b - 2560) * 256 + t);
  } else if (b < 3200) {
    cvt8(Wq, Wqb, (b - 3072) * 256 + t);
  } else if (b < 3328) {
    int idx = (b - 3200) * 256 + t;  // 32768
    int n = idx >> 6, d = idx & 63;
    float s = 0.f;
#pragma unroll
    for (int j = 0; j < 8; ++j) s += Wfc[(size_t)n * 512 + j * 64 + d];
    wsum[idx] = s;
  } else {
    int idx = (b - 3328) * 256 + t;  // 262144
    int s = idx >> 9, c = idx & 511;
    float f = expf(-(float)(c >> 1) * LN10K_OVER_256);
    float ang = (float)s * f;
    pe[idx] = (c & 1) ? cosf(ang) : sinf(ang);
  }
}

// ============ attn_g: per-group attention + fused LN1 (128 blocks) ============
__global__ __launch_bounds__(256) void attn_g(
    const short* __restrict__ qb, const float* __restrict__ x,
    const float* __restrict__ wsum, const float* __restrict__ g1,
    const float* __restrict__ be1, short* __restrict__ o1b) {
  int g = blockIdx.x;
  int hw = g >> 3, i = g & 7;
  int t = threadIdx.x;
  __shared__ short sl[512 * 72];
  __shared__ float a_[512];
  __shared__ float adist_[512];
  __shared__ float pctx[4][64];
  __shared__ float gb[1024];
  __shared__ float redA[4], redB[4], redMS[2];
  __shared__ float ctxs[64];

  gb[t] = g1[t]; gb[t + 256] = g1[t + 256];
  gb[512 + t] = be1[t]; gb[768 + t] = be1[t + 256];

  {
    const short* qsrc = qb + ((size_t)hw * 512) * 512 + i * 64;
    int chunk = t & 7, jr0 = t >> 3;
#pragma unroll
    for (int rep = 0; rep < 16; ++rep) {
      int j = jr0 + rep * 32;
      *(short8*)&sl[j * 72 + chunk * 8] =
          *(const short8*)(qsrc + (size_t)j * 512 + chunk * 8);
    }
  }
  __syncthreads();

  float r0 = 0.f, r1 = 0.f;
#pragma unroll
  for (int c = 0; c < 8; ++c) {
    union { short8 s8; short e[8]; } u0, u1;
    u0.s8 = *(const short8*)&sl[t * 72 + c * 8];
    u1.s8 = *(const short8*)&sl[(t + 256) * 72 + c * 8];
#pragma unroll
    for (int u = 0; u < 8; ++u) {
      r0 += __bfloat162float(*(__hip_bfloat16*)&u0.e[u]);
      r1 += __bfloat162float(*(__hip_bfloat16*)&u1.e[u]);
    }
  }
  float m = fmaxf(r0, r1);
  for (int off = 32; off; off >>= 1) m = fmaxf(m, __shfl_down(m, off));
  int wid = t >> 6, lane = t & 63;
  if (lane == 0) redA[wid] = m;
  __syncthreads();
  if (t == 0) redMS[0] = fmaxf(fmaxf(redA[0], redA[1]), fmaxf(redA[2], redA[3]));
  __syncthreads();
  float M = redMS[0];
  float e0 = expf(r0 - M), e1 = expf(r1 - M);
  float s = e0 + e1;
  for (int off = 32; off; off >>= 1) s += __shfl_down(s, off);
  if (lane == 0) redB[wid] = s;
  __syncthreads();
  if (t == 0) redMS[1] = redB[0] + redB[1] + redB[2] + redB[3];
  __syncthreads();
  float inv = 1.f / redMS[1];
  a_[t] = e0 * inv;
  a_[t + 256] = e1 * inv;
  __syncthreads();

  {
    int d = t & 63, seg = t >> 6;
    float acc = 0.f;
    for (int mm = seg * 128; mm < seg * 128 + 128; ++mm)
      acc += a_[mm] * __bfloat162float(*(__hip_bfloat16*)&sl[mm * 72 + d]);
    pctx[seg][d] = acc;
  }
  __syncthreads();
  if (t < 64) ctxs[t] = pctx[0][t] + pctx[1][t] + pctx[2][t] + pctx[3][t];
  __syncthreads();

  for (int n = t; n < 512; n += 256) {
    const float4* wr = (const float4*)(wsum + (size_t)n * 64);
    float sa = 0.f;
#pragma unroll
    for (int db = 0; db < 16; ++db) {
      float4 wv = wr[db];
      float4 cv = *(const float4*)&ctxs[db * 4];
      sa += cv.x * wv.x + cv.y * wv.y + cv.z * wv.z + cv.w * wv.w;
    }
    adist_[n] = sa;
  }
  __syncthreads();

  const float4* x4 = (const float4*)x;
  int w = t >> 6;
#pragma unroll 1
  for (int u = 0; u < 16; ++u) {
    int j = i * 64 + w * 16 + u;
    size_t R = (size_t)hw * 512 + j;
    float4 xv0 = x4[R * 128 + lane * 2];
    float4 xv1 = x4[R * 128 + lane * 2 + 1];
    float4 a0 = *(const float4*)&adist_[lane * 8];
    float4 a1 = *(const float4*)&adist_[lane * 8 + 4];
    float v[8] = {xv0.x + a0.x, xv0.y + a0.y, xv0.z + a0.z, xv0.w + a0.w,
                  xv1.x + a1.x, xv1.y + a1.y, xv1.z + a1.z, xv1.w + a1.w};
    float sm_ = 0.f, sq = 0.f;
#pragma unroll
    for (int q = 0; q < 8; ++q) { sm_ += v[q]; sq += v[q] * v[q]; }
    for (int off = 32; off; off >>= 1) {
      sm_ += __shfl_xor(sm_, off);
      sq += __shfl_xor(sq, off);
    }
    float mean = sm_ * (1.f / 512.f);
    float var = sq * (1.f / 512.f) - mean * mean;
    float rinv = rsqrtf(var + 1e-5f);
    union { __hip_bfloat16 h[8]; short8 s8; } ub;
#pragma unroll
    for (int q = 0; q < 8; ++q) {
      int c = lane * 8 + q;
      ub.h[q] = __float2bfloat16((v[q] - mean) * rinv * gb[c] + gb[512 + c]);
    }
    *(short8*)&o1b[R * 512 + lane * 8] = ub.s8;
  }
}

// ============ final LN: out = LN(o1b + f2b); wave-per-row ============
__global__ __launch_bounds__(256) void ln2_fused(
    const short* __restrict__ o1b, const short* __restrict__ f2,
    const float* __restrict__ gamma, const float* __restrict__ beta,
    float* __restrict__ Out) {
  int t = threadIdx.x;
  int wv = t >> 6, lane = t & 63;
  size_t r = (size_t)blockIdx.x * 4 + wv;
  size_t base = r * 512 + lane * 8;
  union { short8 s8; short e[8]; } uo, uf;
  uo.s8 = *(const short8*)&o1b[base];
  uf.s8 = *(const short8*)&f2[base];
  float v[8];
  float s = 0.f, sq = 0.f;
#pragma unroll
  for (int k = 0; k < 8; ++k) {
    v[k] = __bfloat162float(*(__hip_bfloat16*)&uo.e[k]) +
           __bfloat162float(*(__hip_bfloat16*)&uf.e[k]);
    s += v[k];
    sq += v[k] * v[k];
  }
  for (int off = 32; off; off >>= 1) {
    s += __shfl_xor(s, off);
    sq += __shfl_xor(sq, off);
  }
  float mean = s * (1.f / 512.f);
  float var = sq * (1.f / 512.f) - mean * mean;
  float inv = rsqrtf(var + 1e-5f);
  int c0 = lane * 8;
  float4 g0 = *(const float4*)&gamma[c0];
  float4 g1v = *(const float4*)&gamma[c0 + 4];
  float4 b0 = *(const float4*)&beta[c0];
  float4 b1v = *(const float4*)&beta[c0 + 4];
  float4 o0, o1v;
  o0.x = (v[0] - mean) * inv * g0.x + b0.x;
  o0.y = (v[1] - mean) * inv * g0.y + b0.y;
  o0.z = (v[2] - mean) * inv * g0.z + b0.z;
  o0.w = (v[3] - mean) * inv * g0.w + b0.w;
  o1v.x = (v[4] - mean) * inv * g1v.x + b1v.x;
  o1v.y = (v[5] - mean) * inv * g1v.y + b1v.y;
  o1v.z = (v[6] - mean) * inv * g1v.z + b1v.z;
  o1v.w = (v[7] - mean) * inv * g1v.w + b1v.w;
  *(float4*)&Out[base] = o0;
  *(float4*)&Out[base + 4] = o1v;
}

extern "C" void kernel_launch(void* const* d_in, const int* in_sizes, int n_in,
                              void* d_out, int out_size, void* d_ws, size_t ws_size,
                              hipStream_t stream) {
  const float* x   = (const float*)d_in[0];
  const float* Wq  = (const float*)d_in[1];
  const float* Wfc = (const float*)d_in[2];
  const float* W1  = (const float*)d_in[3];
  const float* b1  = (const float*)d_in[4];
  const float* W2  = (const float*)d_in[5];
  const float* b2  = (const float*)d_in[6];
  const float* g1  = (const float*)d_in[7];
  const float* be1 = (const float*)d_in[8];
  const float* g2  = (const float*)d_in[9];
  const float* be2 = (const float*)d_in[10];
  float* out = (float*)d_out;

  char* ws = (char*)d_ws;
  short* h1b  = (short*)(ws);                  // 32 MB
  short* f2b  = (short*)(ws + (32u << 20));    // 8 MB
  short* o1b  = (short*)(ws + (40u << 20));    // 8 MB
  short* W1b  = (short*)(ws + (48u << 20));    // 2 MB
  short* W2b  = (short*)(ws + (50u << 20));    // 2 MB
  short* Wqb  = (short*)(ws + (52u << 20));    // 0.5 MB
  short* xb   = (short*)(ws + (53u << 20));    // 8 MB
  short* qb   = (short*)(ws + (61u << 20));    // 8 MB
  float* wsum = (float*)(ws + (69u << 20));    // 128 KB
  float* pe   = (float*)(ws + (69u << 20) + (128u << 10));  // 1 MB

  // 1. converts + wfc fold + PE table
  prep<<<4352, 256, 0, stream>>>(x, W1, W2, Wq, Wfc, xb, W1b, W2b, Wqb, wsum, pe);
  // 2. qb = xb @ Wqb^T + pe
  gemm128<0, 16><<<dim3(4, 64), 256, 0, stream>>>(
      xb, Wqb, pe, qb, 512, 512, 512);
  // 3. per-group attention + fused LN1 -> o1b
  attn_g<<<128, 256, 0, stream>>>(qb, x, wsum, g1, be1, o1b);
  // 4. h1b = relu(o1b @ W1b^T + b1); single-phase gemm256
  gemm256<1, 16><<<dim3(8, 32), 512, 0, stream>>>(
      o1b, W1b, b1, h1b, 2048, 512, 512);
  // 5. f2b = h1b @ W2b^T + b2; BK=64, 32 K-tiles
  gemm128x64<32><<<dim3(4, 64), 256, 0, stream>>>(
      h1b, W2b, b2, f2b, 512, 2048, 2048);
  // 6. out = LN(o1b + f2b)
  ln2_fused<<<2048, 256, 0, stream>>>(o1b, f2b, g2, be2, out);
}